// Round 1
// baseline (1025.461 us; speedup 1.0000x reference)
//
#include <hip/hip_runtime.h>
#include <math.h>

constexpr float NEG_SLOPE = 0.2f;
constexpr float EPS_BN = 1e-5f;
constexpr float EPS_SM = 1e-16f;

__device__ __forceinline__ float lrelu(float x){ return x >= 0.f ? x : NEG_SLOPE * x; }

// ---------------- utility ----------------
__global__ void k_zero_i32(int* p, int n){
  int i = blockIdx.x * blockDim.x + threadIdx.x;
  if (i < n) p[i] = 0;
}
__global__ void k_zero_f32(float* p, int n){
  int i = blockIdx.x * blockDim.x + threadIdx.x;
  if (i < n) p[i] = 0.f;
}

// ---------------- CSR build (dst -> list of src), incl. self loops ----------------
__global__ void k_count(const int* __restrict__ ei, int E, int N, int* __restrict__ cnt){
  int e = blockIdx.x * blockDim.x + threadIdx.x;
  if (e >= E + N) return;
  int dst = (e < E) ? ei[E + e] : (e - E);
  atomicAdd(&cnt[dst], 1);
}

__global__ __launch_bounds__(256) void k_scan(const int* __restrict__ cnt, int* __restrict__ ptr,
                                              int* __restrict__ cursor, int n, int total){
  __shared__ int part[256];
  __shared__ int pre[256];
  int t = threadIdx.x;
  int chunk = (n + 255) / 256;
  int b = t * chunk, e = min(n, b + chunk);
  int s = 0;
  for (int i = b; i < e; i++) s += cnt[i];
  part[t] = s;
  __syncthreads();
  if (t == 0){ int a = 0; for (int i = 0; i < 256; i++){ pre[i] = a; a += part[i]; } }
  __syncthreads();
  int run = pre[t];
  for (int i = b; i < e; i++){ int c = cnt[i]; ptr[i] = run; cursor[i] = run; run += c; }
  if (t == 255) ptr[n] = total;
}

__global__ void k_fill(const int* __restrict__ ei, int E, int N,
                       int* __restrict__ cursor, int* __restrict__ csr_src){
  int e = blockIdx.x * blockDim.x + threadIdx.x;
  if (e >= E + N) return;
  int src, dst;
  if (e < E){ src = ei[e]; dst = ei[E + e]; } else { src = e - E; dst = e - E; }
  int slot = atomicAdd(&cursor[dst], 1);
  csr_src[slot] = src;
}

// ---------------- GEMM: Hout[N,256] = X[N,K] @ W[K,256], f32 ----------------
__global__ __launch_bounds__(256) void k_gemm(const float* __restrict__ X, const float* __restrict__ W,
                                              float* __restrict__ Hout, int nrows, int K){
  __shared__ float At[64][68];  // [k][m], padded
  __shared__ float Bs[64][68];  // [k][n], padded
  int tid = threadIdx.x;
  int m0 = blockIdx.x * 64;
  int n0 = blockIdx.y * 64;
  int tx = tid & 15, ty = tid >> 4;
  int lr = tid >> 4;        // 0..15
  int lc = (tid & 15) * 4;  // 0..60
  float acc[4][4] = {{0.f}};
  for (int k0 = 0; k0 < K; k0 += 64){
    #pragma unroll
    for (int q = 0; q < 4; q++){
      int r = lr + q * 16;
      int gr = m0 + r;
      float4 v = make_float4(0.f, 0.f, 0.f, 0.f);
      if (gr < nrows) v = *(const float4*)(X + (size_t)gr * K + k0 + lc);
      At[lc + 0][r] = v.x; At[lc + 1][r] = v.y; At[lc + 2][r] = v.z; At[lc + 3][r] = v.w;
      float4 w = *(const float4*)(W + (size_t)(k0 + r) * 256 + n0 + lc);
      *(float4*)&Bs[r][lc] = w;
    }
    __syncthreads();
    #pragma unroll 8
    for (int kk = 0; kk < 64; kk++){
      float4 a4 = *(const float4*)&At[kk][ty * 4];
      float4 b4 = *(const float4*)&Bs[kk][tx * 4];
      float a[4] = {a4.x, a4.y, a4.z, a4.w};
      float b[4] = {b4.x, b4.y, b4.z, b4.w};
      #pragma unroll
      for (int i = 0; i < 4; i++)
        #pragma unroll
        for (int j = 0; j < 4; j++)
          acc[i][j] += a[i] * b[j];
    }
    __syncthreads();
  }
  #pragma unroll
  for (int i = 0; i < 4; i++){
    int gr = m0 + ty * 4 + i;
    if (gr < nrows)
      *(float4*)(Hout + (size_t)gr * 256 + n0 + tx * 4) =
          make_float4(acc[i][0], acc[i][1], acc[i][2], acc[i][3]);
  }
}

// ---------------- per-node attention coefficients a_l, a_r ----------------
__global__ __launch_bounds__(256) void k_attn(const float* __restrict__ h,
    const float* __restrict__ a_s, const float* __restrict__ a_d,
    float* __restrict__ al, float* __restrict__ ar, int N){
  int gw = (blockIdx.x * blockDim.x + threadIdx.x) >> 6;
  int lane = threadIdx.x & 63;
  if (gw >= N) return;
  const float* hr = h + (size_t)gw * 256;
  float sa[4], sd[4];
  #pragma unroll
  for (int hd = 0; hd < 4; hd++){
    float v = hr[hd * 64 + lane];
    sa[hd] = v * a_s[hd * 64 + lane];
    sd[hd] = v * a_d[hd * 64 + lane];
  }
  #pragma unroll
  for (int off = 32; off > 0; off >>= 1){
    #pragma unroll
    for (int hd = 0; hd < 4; hd++){
      sa[hd] += __shfl_xor(sa[hd], off);
      sd[hd] += __shfl_xor(sd[hd], off);
    }
  }
  if (lane == 0){
    #pragma unroll
    for (int hd = 0; hd < 4; hd++){ al[gw * 4 + hd] = sa[hd]; ar[gw * 4 + hd] = sd[hd]; }
  }
}

// ---------------- per-node softmax + aggregate (wave per node) ----------------
__global__ __launch_bounds__(256) void k_node(const int* __restrict__ ptr,
    const int* __restrict__ csr, const float* __restrict__ h,
    const float* __restrict__ al, const float* __restrict__ ar,
    const float* __restrict__ bias, float* __restrict__ out, int N){
  int n = (blockIdx.x * blockDim.x + threadIdx.x) >> 6;
  int lane = threadIdx.x & 63;
  if (n >= N) return;
  int beg = ptr[n], end = ptr[n + 1];
  float ar0 = ar[n * 4 + 0], ar1 = ar[n * 4 + 1], ar2 = ar[n * 4 + 2], ar3 = ar[n * 4 + 3];

  // pass 1: segment max per head (lanes parallel over edges)
  float m0 = -1e30f, m1 = -1e30f, m2 = -1e30f, m3 = -1e30f;
  for (int i = beg + lane; i < end; i += 64){
    int s = csr[i];
    m0 = fmaxf(m0, lrelu(al[s * 4 + 0] + ar0));
    m1 = fmaxf(m1, lrelu(al[s * 4 + 1] + ar1));
    m2 = fmaxf(m2, lrelu(al[s * 4 + 2] + ar2));
    m3 = fmaxf(m3, lrelu(al[s * 4 + 3] + ar3));
  }
  #pragma unroll
  for (int off = 32; off > 0; off >>= 1){
    m0 = fmaxf(m0, __shfl_xor(m0, off));
    m1 = fmaxf(m1, __shfl_xor(m1, off));
    m2 = fmaxf(m2, __shfl_xor(m2, off));
    m3 = fmaxf(m3, __shfl_xor(m3, off));
  }

  // pass 2: exp-sum per head
  float d0 = 0.f, d1 = 0.f, d2 = 0.f, d3 = 0.f;
  for (int i = beg + lane; i < end; i += 64){
    int s = csr[i];
    d0 += __expf(lrelu(al[s * 4 + 0] + ar0) - m0);
    d1 += __expf(lrelu(al[s * 4 + 1] + ar1) - m1);
    d2 += __expf(lrelu(al[s * 4 + 2] + ar2) - m2);
    d3 += __expf(lrelu(al[s * 4 + 3] + ar3) - m3);
  }
  #pragma unroll
  for (int off = 32; off > 0; off >>= 1){
    d0 += __shfl_xor(d0, off);
    d1 += __shfl_xor(d1, off);
    d2 += __shfl_xor(d2, off);
    d3 += __shfl_xor(d3, off);
  }
  float i0 = 1.f / (d0 + EPS_SM), i1 = 1.f / (d1 + EPS_SM);
  float i2 = 1.f / (d2 + EPS_SM), i3 = 1.f / (d3 + EPS_SM);

  // pass 3: aggregate. lane -> (head = lane>>4, 4 channels cg..cg+3)
  int hd = lane >> 4;
  int cg = (lane & 15) * 4;
  float arh = hd == 0 ? ar0 : hd == 1 ? ar1 : hd == 2 ? ar2 : ar3;
  float mh  = hd == 0 ? m0  : hd == 1 ? m1  : hd == 2 ? m2  : m3;
  float ih  = hd == 0 ? i0  : hd == 1 ? i1  : hd == 2 ? i2  : i3;
  float ax = 0.f, ay = 0.f, az = 0.f, aw = 0.f;
  for (int i = beg; i < end; i++){
    int s = csr[i];
    float w = __expf(lrelu(al[s * 4 + hd] + arh) - mh) * ih;
    float4 hv = *(const float4*)(h + (size_t)s * 256 + hd * 64 + cg);
    ax += hv.x * w; ay += hv.y * w; az += hv.z * w; aw += hv.w * w;
  }
  // sum over heads: lanes differing in bits 4,5 hold same channels
  #pragma unroll
  for (int off = 16; off <= 32; off <<= 1){
    ax += __shfl_xor(ax, off);
    ay += __shfl_xor(ay, off);
    az += __shfl_xor(az, off);
    aw += __shfl_xor(aw, off);
  }
  if (lane < 16){
    float4 b4 = *(const float4*)(bias + cg);
    *(float4*)(out + (size_t)n * 64 + cg) =
        make_float4(ax * 0.25f + b4.x, ay * 0.25f + b4.y, az * 0.25f + b4.z, aw * 0.25f + b4.w);
  }
}

// ---------------- BatchNorm (training-mode stats) ----------------
__global__ __launch_bounds__(256) void k_bnstats(const float* __restrict__ x, int N,
                                                 float* __restrict__ gsum, float* __restrict__ gsq){
  int c = threadIdx.x & 63;
  int rg = threadIdx.x >> 6;  // 0..3
  float s = 0.f, q = 0.f;
  for (int r = blockIdx.x * 4 + rg; r < N; r += gridDim.x * 4){
    float v = x[(size_t)r * 64 + c];
    s += v; q += v * v;
  }
  __shared__ float ls[4][64], lq[4][64];
  ls[rg][c] = s; lq[rg][c] = q;
  __syncthreads();
  if (rg == 0){
    s = ls[0][c] + ls[1][c] + ls[2][c] + ls[3][c];
    q = lq[0][c] + lq[1][c] + lq[2][c] + lq[3][c];
    atomicAdd(&gsum[c], s);
    atomicAdd(&gsq[c], q);
  }
}

__global__ void k_bnfin(const float* __restrict__ gsum, const float* __restrict__ gsq,
                        float* __restrict__ mu, float* __restrict__ rstd, int N){
  int c = threadIdx.x;
  if (c < 64){
    float m = gsum[c] / (float)N;
    float v = gsq[c] / (float)N - m * m;
    mu[c] = m;
    rstd[c] = rsqrtf(v + EPS_BN);
  }
}

__global__ void k_bnapply(const float* __restrict__ x, const float* __restrict__ mu,
                          const float* __restrict__ rstd, const float* __restrict__ g,
                          const float* __restrict__ be, float* __restrict__ y, int total){
  int i = blockIdx.x * blockDim.x + threadIdx.x;
  if (i >= total) return;
  int c = i & 63;
  float v = (x[i] - mu[c]) * rstd[c] * g[c] + be[c];
  y[i] = fmaxf(v, 0.f);
}

// ---------------- launcher ----------------
extern "C" void kernel_launch(void* const* d_in, const int* in_sizes, int n_in,
                              void* d_out, int out_size, void* d_ws, size_t ws_size,
                              hipStream_t stream){
  const float* x  = (const float*)d_in[0];
  const int*   ei = (const int*)d_in[1];
  const float* W[3]  = {(const float*)d_in[2], (const float*)d_in[6],  (const float*)d_in[10]};
  const float* AS[3] = {(const float*)d_in[3], (const float*)d_in[7],  (const float*)d_in[11]};
  const float* AD[3] = {(const float*)d_in[4], (const float*)d_in[8],  (const float*)d_in[12]};
  const float* BI[3] = {(const float*)d_in[5], (const float*)d_in[9],  (const float*)d_in[13]};
  const float* G[2]  = {(const float*)d_in[14], (const float*)d_in[16]};
  const float* BE[2] = {(const float*)d_in[15], (const float*)d_in[17]};
  const int N = in_sizes[0] / 256;
  const int E = in_sizes[1] / 2;
  const int EN = E + N;

  char* wsb = (char*)d_ws;
  size_t off = 0;
  auto alloc = [&](size_t bytes) -> char* {
    char* p = wsb + off;
    off = (off + bytes + 255) & ~(size_t)255;
    return p;
  };
  int* cnt     = (int*)alloc((size_t)N * 4);
  int* cursor  = (int*)alloc((size_t)N * 4);
  int* rowptr  = (int*)alloc((size_t)(N + 1) * 4);
  int* csr     = (int*)alloc((size_t)EN * 4);
  float* hbuf  = (float*)alloc((size_t)N * 256 * 4);
  float* al    = (float*)alloc((size_t)N * 4 * 4);
  float* ar    = (float*)alloc((size_t)N * 4 * 4);
  float* bufA  = (float*)alloc((size_t)N * 64 * 4);
  float* bufB  = (float*)alloc((size_t)N * 64 * 4);
  float* bn    = (float*)alloc(256 * 4);   // gsum0,gsq0,gsum1,gsq1
  float* murs  = (float*)alloc(128 * 4);   // mu, rstd

  // CSR build (edge structure is static but ws is re-poisoned every call)
  k_zero_i32<<<(N + 255) / 256, 256, 0, stream>>>(cnt, N);
  k_zero_f32<<<1, 256, 0, stream>>>(bn, 256);
  k_count<<<(EN + 255) / 256, 256, 0, stream>>>(ei, E, N, cnt);
  k_scan<<<1, 256, 0, stream>>>(cnt, rowptr, cursor, N, EN);
  k_fill<<<(EN + 255) / 256, 256, 0, stream>>>(ei, E, N, cursor, csr);

  const float* lin = x;
  for (int l = 0; l < 3; l++){
    int K = (l == 0) ? 256 : 64;
    dim3 gg((N + 63) / 64, 4);
    k_gemm<<<gg, 256, 0, stream>>>(lin, W[l], hbuf, N, K);
    k_attn<<<(N + 3) / 4, 256, 0, stream>>>(hbuf, AS[l], AD[l], al, ar, N);
    float* outp = (l == 2) ? (float*)d_out : bufA;
    k_node<<<(N + 3) / 4, 256, 0, stream>>>(rowptr, csr, hbuf, al, ar, BI[l], outp, N);
    if (l < 2){
      float* gsum = bn + l * 128;
      float* gsq  = gsum + 64;
      k_bnstats<<<128, 256, 0, stream>>>(bufA, N, gsum, gsq);
      k_bnfin<<<1, 64, 0, stream>>>(gsum, gsq, murs, murs + 64, N);
      k_bnapply<<<(N * 64 + 255) / 256, 256, 0, stream>>>(bufA, murs, murs + 64, G[l], BE[l], bufB, N * 64);
      lin = bufB;
    }
  }
}

// Round 2
// 812.881 us; speedup vs baseline: 1.2615x; 1.2615x over previous
//
#include <hip/hip_runtime.h>
#include <hip/hip_fp16.h>
#include <math.h>

constexpr float NEG_SLOPE = 0.2f;
constexpr float EPS_BN = 1e-5f;
constexpr float EPS_SM = 1e-16f;

__device__ __forceinline__ float lrelu(float x){ return x >= 0.f ? x : NEG_SLOPE * x; }

// ---------------- utility ----------------
__global__ void k_zero_i32(int* p, int n){
  int i = blockIdx.x * blockDim.x + threadIdx.x;
  if (i < n) p[i] = 0;
}
__global__ void k_zero_f32(float* p, int n){
  int i = blockIdx.x * blockDim.x + threadIdx.x;
  if (i < n) p[i] = 0.f;
}

// ---------------- CSR build (dst -> list of src), incl. self loops ----------------
__global__ void k_count(const int* __restrict__ ei, int E, int N, int* __restrict__ cnt){
  int e = blockIdx.x * blockDim.x + threadIdx.x;
  if (e >= E + N) return;
  int dst = (e < E) ? ei[E + e] : (e - E);
  atomicAdd(&cnt[dst], 1);
}

__global__ __launch_bounds__(256) void k_scan(const int* __restrict__ cnt, int* __restrict__ ptr,
                                              int* __restrict__ cursor, int n, int total){
  __shared__ int part[256];
  __shared__ int pre[256];
  int t = threadIdx.x;
  int chunk = (n + 255) / 256;
  int b = t * chunk, e = min(n, b + chunk);
  int s = 0;
  for (int i = b; i < e; i++) s += cnt[i];
  part[t] = s;
  __syncthreads();
  if (t == 0){ int a = 0; for (int i = 0; i < 256; i++){ pre[i] = a; a += part[i]; } }
  __syncthreads();
  int run = pre[t];
  for (int i = b; i < e; i++){ int c = cnt[i]; ptr[i] = run; cursor[i] = run; run += c; }
  if (t == 255) ptr[n] = total;
}

__global__ void k_fill(const int* __restrict__ ei, int E, int N,
                       int* __restrict__ cursor, int* __restrict__ csr_src){
  int e = blockIdx.x * blockDim.x + threadIdx.x;
  if (e >= E + N) return;
  int src, dst;
  if (e < E){ src = ei[e]; dst = ei[E + e]; } else { src = e - E; dst = e - E; }
  int slot = atomicAdd(&cursor[dst], 1);
  csr_src[slot] = src;
}

// ---------------- fused GEMM + attention coeffs + fp16 convert ----------------
// Hout block col range = head*64 .. head*64+63 (blockIdx.y == head).
// Epilogue: al[n,head] = sum_c h*a_s, ar[n,head] = sum_c h*a_d, hb = fp16(h).
__global__ __launch_bounds__(256) void k_gemm(const float* __restrict__ X, const float* __restrict__ W,
                                              const float* __restrict__ a_s, const float* __restrict__ a_d,
                                              __half* __restrict__ hb, float* __restrict__ al,
                                              float* __restrict__ ar, int nrows, int K){
  __shared__ float At[64][68];  // [k][m], padded
  __shared__ float Bs[64][68];  // [k][n], padded
  int tid = threadIdx.x;
  int m0 = blockIdx.x * 64;
  int head = blockIdx.y;
  int n0 = head * 64;
  int tx = tid & 15, ty = tid >> 4;
  int lr = ty;          // 0..15
  int lc = tx * 4;      // 0..60
  float acc[4][4] = {{0.f}};
  for (int k0 = 0; k0 < K; k0 += 64){
    #pragma unroll
    for (int q = 0; q < 4; q++){
      int r = lr + q * 16;
      int gr = m0 + r;
      float4 v = make_float4(0.f, 0.f, 0.f, 0.f);
      if (gr < nrows) v = *(const float4*)(X + (size_t)gr * K + k0 + lc);
      At[lc + 0][r] = v.x; At[lc + 1][r] = v.y; At[lc + 2][r] = v.z; At[lc + 3][r] = v.w;
      float4 w = *(const float4*)(W + (size_t)(k0 + r) * 256 + n0 + lc);
      *(float4*)&Bs[r][lc] = w;
    }
    __syncthreads();
    #pragma unroll 8
    for (int kk = 0; kk < 64; kk++){
      float4 a4 = *(const float4*)&At[kk][ty * 4];
      float4 b4 = *(const float4*)&Bs[kk][tx * 4];
      float a[4] = {a4.x, a4.y, a4.z, a4.w};
      float b[4] = {b4.x, b4.y, b4.z, b4.w};
      #pragma unroll
      for (int i = 0; i < 4; i++)
        #pragma unroll
        for (int j = 0; j < 4; j++)
          acc[i][j] += a[i] * b[j];
    }
    __syncthreads();
  }
  // epilogue: attention coefficients (reduce over this block's 64 cols = full head)
  float4 asv = *(const float4*)(a_s + head * 64 + tx * 4);
  float4 adv = *(const float4*)(a_d + head * 64 + tx * 4);
  #pragma unroll
  for (int i = 0; i < 4; i++){
    float sl = acc[i][0] * asv.x + acc[i][1] * asv.y + acc[i][2] * asv.z + acc[i][3] * asv.w;
    float sr = acc[i][0] * adv.x + acc[i][1] * adv.y + acc[i][2] * adv.z + acc[i][3] * adv.w;
    #pragma unroll
    for (int off = 1; off < 16; off <<= 1){
      sl += __shfl_xor(sl, off);
      sr += __shfl_xor(sr, off);
    }
    int gr = m0 + ty * 4 + i;
    if (tx == 0 && gr < nrows){
      al[(size_t)gr * 4 + head] = sl;
      ar[(size_t)gr * 4 + head] = sr;
    }
  }
  // epilogue: fp16 h
  #pragma unroll
  for (int i = 0; i < 4; i++){
    int gr = m0 + ty * 4 + i;
    if (gr < nrows){
      ushort4 u;
      u.x = __half_as_ushort(__float2half(acc[i][0]));
      u.y = __half_as_ushort(__float2half(acc[i][1]));
      u.z = __half_as_ushort(__float2half(acc[i][2]));
      u.w = __half_as_ushort(__float2half(acc[i][3]));
      *(ushort4*)(hb + (size_t)gr * 256 + head * 64 + tx * 4) = u;
    }
  }
}

// ---------------- per-node softmax + aggregate (wave per node) ----------------
__global__ __launch_bounds__(256) void k_node(const int* __restrict__ ptr,
    const int* __restrict__ csr, const __half* __restrict__ hb,
    const float* __restrict__ al, const float* __restrict__ ar,
    const float* __restrict__ bias, float* __restrict__ out, int N){
  int n = (blockIdx.x * blockDim.x + threadIdx.x) >> 6;
  int lane = threadIdx.x & 63;
  if (n >= N) return;
  int beg = ptr[n], end = ptr[n + 1];
  int deg = end - beg;
  float4 arv = *(const float4*)(ar + (size_t)n * 4);
  int hd = lane >> 4;
  int cg = (lane & 15) * 4;
  float ax = 0.f, ay = 0.f, az = 0.f, aw = 0.f;

  if (deg <= 64){
    // lane-parallel preload: each lane owns one edge
    int idx = beg + lane;
    bool act = idx < end;
    int mye = act ? csr[idx] : 0;
    float e0 = -1e30f, e1 = -1e30f, e2 = -1e30f, e3 = -1e30f;
    if (act){
      float4 av = *(const float4*)(al + (size_t)mye * 4);
      e0 = lrelu(av.x + arv.x); e1 = lrelu(av.y + arv.y);
      e2 = lrelu(av.z + arv.z); e3 = lrelu(av.w + arv.w);
    }
    float m0 = e0, m1 = e1, m2 = e2, m3 = e3;
    #pragma unroll
    for (int off = 32; off > 0; off >>= 1){
      m0 = fmaxf(m0, __shfl_xor(m0, off));
      m1 = fmaxf(m1, __shfl_xor(m1, off));
      m2 = fmaxf(m2, __shfl_xor(m2, off));
      m3 = fmaxf(m3, __shfl_xor(m3, off));
    }
    float w0 = __expf(e0 - m0), w1 = __expf(e1 - m1);
    float w2 = __expf(e2 - m2), w3 = __expf(e3 - m3);   // inactive lanes -> exp(-1e30)=0
    float d0 = w0, d1 = w1, d2 = w2, d3 = w3;
    #pragma unroll
    for (int off = 32; off > 0; off >>= 1){
      d0 += __shfl_xor(d0, off);
      d1 += __shfl_xor(d1, off);
      d2 += __shfl_xor(d2, off);
      d3 += __shfl_xor(d3, off);
    }
    // normalized weights for my edge, all 4 heads
    float wn0 = w0 / (d0 + EPS_SM), wn1 = w1 / (d1 + EPS_SM);
    float wn2 = w2 / (d2 + EPS_SM), wn3 = w3 / (d3 + EPS_SM);
    // aggregation: src + weight via shfl (no memory dependence), fp16 gather
    #pragma unroll 2
    for (int j = 0; j < deg; j++){
      int s = __shfl(mye, j);
      float wa = __shfl(wn0, j), wb = __shfl(wn1, j);
      float wc = __shfl(wn2, j), wd = __shfl(wn3, j);
      float w = hd == 0 ? wa : hd == 1 ? wb : hd == 2 ? wc : wd;
      ushort4 u = *(const ushort4*)(hb + (size_t)s * 256 + hd * 64 + cg);
      ax += __half2float(__ushort_as_half(u.x)) * w;
      ay += __half2float(__ushort_as_half(u.y)) * w;
      az += __half2float(__ushort_as_half(u.z)) * w;
      aw += __half2float(__ushort_as_half(u.w)) * w;
    }
  } else {
    // fallback: 3-pass (rare; deg > 64)
    float m0 = -1e30f, m1 = -1e30f, m2 = -1e30f, m3 = -1e30f;
    for (int i = beg + lane; i < end; i += 64){
      int s = csr[i];
      float4 av = *(const float4*)(al + (size_t)s * 4);
      m0 = fmaxf(m0, lrelu(av.x + arv.x));
      m1 = fmaxf(m1, lrelu(av.y + arv.y));
      m2 = fmaxf(m2, lrelu(av.z + arv.z));
      m3 = fmaxf(m3, lrelu(av.w + arv.w));
    }
    #pragma unroll
    for (int off = 32; off > 0; off >>= 1){
      m0 = fmaxf(m0, __shfl_xor(m0, off));
      m1 = fmaxf(m1, __shfl_xor(m1, off));
      m2 = fmaxf(m2, __shfl_xor(m2, off));
      m3 = fmaxf(m3, __shfl_xor(m3, off));
    }
    float d0 = 0.f, d1 = 0.f, d2 = 0.f, d3 = 0.f;
    for (int i = beg + lane; i < end; i += 64){
      int s = csr[i];
      float4 av = *(const float4*)(al + (size_t)s * 4);
      d0 += __expf(lrelu(av.x + arv.x) - m0);
      d1 += __expf(lrelu(av.y + arv.y) - m1);
      d2 += __expf(lrelu(av.z + arv.z) - m2);
      d3 += __expf(lrelu(av.w + arv.w) - m3);
    }
    #pragma unroll
    for (int off = 32; off > 0; off >>= 1){
      d0 += __shfl_xor(d0, off);
      d1 += __shfl_xor(d1, off);
      d2 += __shfl_xor(d2, off);
      d3 += __shfl_xor(d3, off);
    }
    float i0 = 1.f / (d0 + EPS_SM), i1 = 1.f / (d1 + EPS_SM);
    float i2 = 1.f / (d2 + EPS_SM), i3 = 1.f / (d3 + EPS_SM);
    float arh = hd == 0 ? arv.x : hd == 1 ? arv.y : hd == 2 ? arv.z : arv.w;
    float mh  = hd == 0 ? m0 : hd == 1 ? m1 : hd == 2 ? m2 : m3;
    float ih  = hd == 0 ? i0 : hd == 1 ? i1 : hd == 2 ? i2 : i3;
    for (int i = beg; i < end; i++){
      int s = csr[i];
      float w = __expf(lrelu(al[(size_t)s * 4 + hd] + arh) - mh) * ih;
      ushort4 u = *(const ushort4*)(hb + (size_t)s * 256 + hd * 64 + cg);
      ax += __half2float(__ushort_as_half(u.x)) * w;
      ay += __half2float(__ushort_as_half(u.y)) * w;
      az += __half2float(__ushort_as_half(u.z)) * w;
      aw += __half2float(__ushort_as_half(u.w)) * w;
    }
  }

  // sum over heads: lanes differing in bits 4,5 hold same channels
  #pragma unroll
  for (int off = 16; off <= 32; off <<= 1){
    ax += __shfl_xor(ax, off);
    ay += __shfl_xor(ay, off);
    az += __shfl_xor(az, off);
    aw += __shfl_xor(aw, off);
  }
  if (lane < 16){
    float4 b4 = *(const float4*)(bias + cg);
    *(float4*)(out + (size_t)n * 64 + cg) =
        make_float4(ax * 0.25f + b4.x, ay * 0.25f + b4.y, az * 0.25f + b4.z, aw * 0.25f + b4.w);
  }
}

// ---------------- BatchNorm (training-mode stats) ----------------
__global__ __launch_bounds__(256) void k_bnstats(const float* __restrict__ x, int N,
                                                 float* __restrict__ gsum, float* __restrict__ gsq){
  int c = threadIdx.x & 63;
  int rg = threadIdx.x >> 6;  // 0..3
  float s = 0.f, q = 0.f;
  for (int r = blockIdx.x * 4 + rg; r < N; r += gridDim.x * 4){
    float v = x[(size_t)r * 64 + c];
    s += v; q += v * v;
  }
  __shared__ float ls[4][64], lq[4][64];
  ls[rg][c] = s; lq[rg][c] = q;
  __syncthreads();
  if (rg == 0){
    s = ls[0][c] + ls[1][c] + ls[2][c] + ls[3][c];
    q = lq[0][c] + lq[1][c] + lq[2][c] + lq[3][c];
    atomicAdd(&gsum[c], s);
    atomicAdd(&gsq[c], q);
  }
}

__global__ void k_bnfin(const float* __restrict__ gsum, const float* __restrict__ gsq,
                        float* __restrict__ mu, float* __restrict__ rstd, int N){
  int c = threadIdx.x;
  if (c < 64){
    float m = gsum[c] / (float)N;
    float v = gsq[c] / (float)N - m * m;
    mu[c] = m;
    rstd[c] = rsqrtf(v + EPS_BN);
  }
}

__global__ void k_bnapply(const float* __restrict__ x, const float* __restrict__ mu,
                          const float* __restrict__ rstd, const float* __restrict__ g,
                          const float* __restrict__ be, float* __restrict__ y, int total){
  int i = blockIdx.x * blockDim.x + threadIdx.x;
  if (i >= total) return;
  int c = i & 63;
  float v = (x[i] - mu[c]) * rstd[c] * g[c] + be[c];
  y[i] = fmaxf(v, 0.f);
}

// ---------------- launcher ----------------
extern "C" void kernel_launch(void* const* d_in, const int* in_sizes, int n_in,
                              void* d_out, int out_size, void* d_ws, size_t ws_size,
                              hipStream_t stream){
  const float* x  = (const float*)d_in[0];
  const int*   ei = (const int*)d_in[1];
  const float* W[3]  = {(const float*)d_in[2], (const float*)d_in[6],  (const float*)d_in[10]};
  const float* AS[3] = {(const float*)d_in[3], (const float*)d_in[7],  (const float*)d_in[11]};
  const float* AD[3] = {(const float*)d_in[4], (const float*)d_in[8],  (const float*)d_in[12]};
  const float* BI[3] = {(const float*)d_in[5], (const float*)d_in[9],  (const float*)d_in[13]};
  const float* G[2]  = {(const float*)d_in[14], (const float*)d_in[16]};
  const float* BE[2] = {(const float*)d_in[15], (const float*)d_in[17]};
  const int N = in_sizes[0] / 256;
  const int E = in_sizes[1] / 2;
  const int EN = E + N;

  char* wsb = (char*)d_ws;
  size_t off = 0;
  auto alloc = [&](size_t bytes) -> char* {
    char* p = wsb + off;
    off = (off + bytes + 255) & ~(size_t)255;
    return p;
  };
  int* cnt     = (int*)alloc((size_t)N * 4);
  int* cursor  = (int*)alloc((size_t)N * 4);
  int* rowptr  = (int*)alloc((size_t)(N + 1) * 4);
  int* csr     = (int*)alloc((size_t)EN * 4);
  __half* hb   = (__half*)alloc((size_t)N * 256 * 2);
  float* al    = (float*)alloc((size_t)N * 4 * 4);
  float* ar    = (float*)alloc((size_t)N * 4 * 4);
  float* bufA  = (float*)alloc((size_t)N * 64 * 4);
  float* bufB  = (float*)alloc((size_t)N * 64 * 4);
  float* bn    = (float*)alloc(256 * 4);   // gsum0,gsq0,gsum1,gsq1
  float* murs  = (float*)alloc(128 * 4);   // mu, rstd

  // CSR build (edge structure is static but ws is re-poisoned every call)
  k_zero_i32<<<(N + 255) / 256, 256, 0, stream>>>(cnt, N);
  k_zero_f32<<<1, 256, 0, stream>>>(bn, 256);
  k_count<<<(EN + 255) / 256, 256, 0, stream>>>(ei, E, N, cnt);
  k_scan<<<1, 256, 0, stream>>>(cnt, rowptr, cursor, N, EN);
  k_fill<<<(EN + 255) / 256, 256, 0, stream>>>(ei, E, N, cursor, csr);

  const float* lin = x;
  for (int l = 0; l < 3; l++){
    int K = (l == 0) ? 256 : 64;
    dim3 gg((N + 63) / 64, 4);
    k_gemm<<<gg, 256, 0, stream>>>(lin, W[l], AS[l], AD[l], hb, al, ar, N, K);
    float* outp = (l == 2) ? (float*)d_out : bufA;
    k_node<<<(N + 3) / 4, 256, 0, stream>>>(rowptr, csr, hb, al, ar, BI[l], outp, N);
    if (l < 2){
      float* gsum = bn + l * 128;
      float* gsq  = gsum + 64;
      k_bnstats<<<128, 256, 0, stream>>>(bufA, N, gsum, gsq);
      k_bnfin<<<1, 64, 0, stream>>>(gsum, gsq, murs, murs + 64, N);
      k_bnapply<<<(N * 64 + 255) / 256, 256, 0, stream>>>(bufA, murs, murs + 64, G[l], BE[l], bufB, N * 64);
      lin = bufB;
    }
  }
}

// Round 3
// 694.556 us; speedup vs baseline: 1.4764x; 1.1704x over previous
//
#include <hip/hip_runtime.h>
#include <hip/hip_fp16.h>
#include <math.h>

constexpr float NEG_SLOPE = 0.2f;
constexpr float EPS_BN = 1e-5f;
constexpr float EPS_SM = 1e-16f;

__device__ __forceinline__ float lrelu(float x){ return x >= 0.f ? x : NEG_SLOPE * x; }

// ---------------- utility ----------------
__global__ void k_zero_i32(int* p, int n){
  int i = blockIdx.x * blockDim.x + threadIdx.x;
  if (i < n) p[i] = 0;
}
__global__ void k_zero_f32(float* p, int n){
  int i = blockIdx.x * blockDim.x + threadIdx.x;
  if (i < n) p[i] = 0.f;
}

// ---------------- CSR build (dst -> list of src), incl. self loops ----------------
__global__ void k_count(const int* __restrict__ ei, int E, int N, int* __restrict__ cnt){
  int e = blockIdx.x * blockDim.x + threadIdx.x;
  if (e >= E + N) return;
  int dst = (e < E) ? ei[E + e] : (e - E);
  atomicAdd(&cnt[dst], 1);
}

// hierarchical exclusive scan over cnt[0..n): 256 blocks x 256 threads
__global__ __launch_bounds__(256) void k_blocksum(const int* __restrict__ cnt, int n, int chunk,
                                                  int* __restrict__ part){
  __shared__ int s[256];
  int b = blockIdx.x, t = threadIdx.x;
  int lo = b * chunk, hi = min(n, lo + chunk);
  int v = 0;
  for (int i = lo + t; i < hi; i += 256) v += cnt[i];
  s[t] = v;
  __syncthreads();
  #pragma unroll
  for (int off = 128; off > 0; off >>= 1){
    if (t < off) s[t] += s[t + off];
    __syncthreads();
  }
  if (t == 0) part[b] = s[0];
}

__global__ __launch_bounds__(256) void k_scanpart(int* __restrict__ part, int* __restrict__ ptr, int n){
  __shared__ int s[256];
  int t = threadIdx.x;
  int v = part[t];
  s[t] = v;
  __syncthreads();
  #pragma unroll
  for (int off = 1; off < 256; off <<= 1){
    int u = (t >= off) ? s[t - off] : 0;
    __syncthreads();
    s[t] += u;
    __syncthreads();
  }
  part[t] = s[t] - v;          // exclusive block prefix
  if (t == 255) ptr[n] = s[255];
}

__global__ __launch_bounds__(256) void k_localscan(const int* __restrict__ cnt, const int* __restrict__ part,
                                                   int n, int chunk, int* __restrict__ ptr,
                                                   int* __restrict__ cursor){
  __shared__ int s[256];
  int b = blockIdx.x, t = threadIdx.x;
  int i = b * chunk + t;     // chunk <= 256 guaranteed by launcher
  int v = (t < chunk && i < n) ? cnt[i] : 0;
  s[t] = v;
  __syncthreads();
  #pragma unroll
  for (int off = 1; off < 256; off <<= 1){
    int u = (t >= off) ? s[t - off] : 0;
    __syncthreads();
    s[t] += u;
    __syncthreads();
  }
  if (t < chunk && i < n){
    int ex = part[b] + s[t] - v;
    ptr[i] = ex;
    cursor[i] = ex;
  }
}

__global__ void k_fill(const int* __restrict__ ei, int E, int N,
                       int* __restrict__ cursor, int* __restrict__ csr_src){
  int e = blockIdx.x * blockDim.x + threadIdx.x;
  if (e >= E + N) return;
  int src, dst;
  if (e < E){ src = ei[e]; dst = ei[E + e]; } else { src = e - E; dst = e - E; }
  int slot = atomicAdd(&cursor[dst], 1);
  csr_src[slot] = src;
}

// ---------------- fused GEMM + attention coeffs + fp16 convert ----------------
__global__ __launch_bounds__(256) void k_gemm(const float* __restrict__ X, const float* __restrict__ W,
                                              const float* __restrict__ a_s, const float* __restrict__ a_d,
                                              __half* __restrict__ hb, float* __restrict__ al,
                                              float* __restrict__ ar, int nrows, int K){
  __shared__ float At[64][68];  // [k][m], padded
  __shared__ float Bs[64][68];  // [k][n], padded
  int tid = threadIdx.x;
  int m0 = blockIdx.x * 64;
  int head = blockIdx.y;
  int n0 = head * 64;
  int tx = tid & 15, ty = tid >> 4;
  int lr = ty;          // 0..15
  int lc = tx * 4;      // 0..60
  float acc[4][4] = {{0.f}};
  for (int k0 = 0; k0 < K; k0 += 64){
    #pragma unroll
    for (int q = 0; q < 4; q++){
      int r = lr + q * 16;
      int gr = m0 + r;
      float4 v = make_float4(0.f, 0.f, 0.f, 0.f);
      if (gr < nrows) v = *(const float4*)(X + (size_t)gr * K + k0 + lc);
      At[lc + 0][r] = v.x; At[lc + 1][r] = v.y; At[lc + 2][r] = v.z; At[lc + 3][r] = v.w;
      float4 w = *(const float4*)(W + (size_t)(k0 + r) * 256 + n0 + lc);
      *(float4*)&Bs[r][lc] = w;
    }
    __syncthreads();
    #pragma unroll 8
    for (int kk = 0; kk < 64; kk++){
      float4 a4 = *(const float4*)&At[kk][ty * 4];
      float4 b4 = *(const float4*)&Bs[kk][tx * 4];
      float a[4] = {a4.x, a4.y, a4.z, a4.w};
      float b[4] = {b4.x, b4.y, b4.z, b4.w};
      #pragma unroll
      for (int i = 0; i < 4; i++)
        #pragma unroll
        for (int j = 0; j < 4; j++)
          acc[i][j] += a[i] * b[j];
    }
    __syncthreads();
  }
  // epilogue: attention coefficients (reduce over this block's 64 cols = full head)
  float4 asv = *(const float4*)(a_s + head * 64 + tx * 4);
  float4 adv = *(const float4*)(a_d + head * 64 + tx * 4);
  #pragma unroll
  for (int i = 0; i < 4; i++){
    float sl = acc[i][0] * asv.x + acc[i][1] * asv.y + acc[i][2] * asv.z + acc[i][3] * asv.w;
    float sr = acc[i][0] * adv.x + acc[i][1] * adv.y + acc[i][2] * adv.z + acc[i][3] * adv.w;
    #pragma unroll
    for (int off = 1; off < 16; off <<= 1){
      sl += __shfl_xor(sl, off);
      sr += __shfl_xor(sr, off);
    }
    int gr = m0 + ty * 4 + i;
    if (tx == 0 && gr < nrows){
      al[(size_t)gr * 4 + head] = sl;
      ar[(size_t)gr * 4 + head] = sr;
    }
  }
  // epilogue: fp16 h
  #pragma unroll
  for (int i = 0; i < 4; i++){
    int gr = m0 + ty * 4 + i;
    if (gr < nrows){
      ushort4 u;
      u.x = __half_as_ushort(__float2half(acc[i][0]));
      u.y = __half_as_ushort(__float2half(acc[i][1]));
      u.z = __half_as_ushort(__float2half(acc[i][2]));
      u.w = __half_as_ushort(__float2half(acc[i][3]));
      *(ushort4*)(hb + (size_t)gr * 256 + head * 64 + tx * 4) = u;
    }
  }
}

// ---------------- per-node softmax + aggregate (wave per node) ----------------
__global__ __launch_bounds__(256) void k_node(const int* __restrict__ ptr,
    const int* __restrict__ csr, const __half* __restrict__ hb,
    const float* __restrict__ al, const float* __restrict__ ar,
    const float* __restrict__ bias, float* __restrict__ out, int N){
  int n = (blockIdx.x * blockDim.x + threadIdx.x) >> 6;
  int lane = threadIdx.x & 63;
  if (n >= N) return;
  int beg = ptr[n], end = ptr[n + 1];
  int deg = end - beg;
  float4 arv = *(const float4*)(ar + (size_t)n * 4);
  int hd = lane >> 4;
  int cg = (lane & 15) * 4;
  float ax = 0.f, ay = 0.f, az = 0.f, aw = 0.f;

  if (deg <= 64){
    int idx = beg + lane;
    bool act = idx < end;
    int mye = act ? csr[idx] : 0;
    float e0 = -1e30f, e1 = -1e30f, e2 = -1e30f, e3 = -1e30f;
    if (act){
      float4 av = *(const float4*)(al + (size_t)mye * 4);
      e0 = lrelu(av.x + arv.x); e1 = lrelu(av.y + arv.y);
      e2 = lrelu(av.z + arv.z); e3 = lrelu(av.w + arv.w);
    }
    float m0 = e0, m1 = e1, m2 = e2, m3 = e3;
    #pragma unroll
    for (int off = 32; off > 0; off >>= 1){
      m0 = fmaxf(m0, __shfl_xor(m0, off));
      m1 = fmaxf(m1, __shfl_xor(m1, off));
      m2 = fmaxf(m2, __shfl_xor(m2, off));
      m3 = fmaxf(m3, __shfl_xor(m3, off));
    }
    float w0 = __expf(e0 - m0), w1 = __expf(e1 - m1);
    float w2 = __expf(e2 - m2), w3 = __expf(e3 - m3);
    float d0 = w0, d1 = w1, d2 = w2, d3 = w3;
    #pragma unroll
    for (int off = 32; off > 0; off >>= 1){
      d0 += __shfl_xor(d0, off);
      d1 += __shfl_xor(d1, off);
      d2 += __shfl_xor(d2, off);
      d3 += __shfl_xor(d3, off);
    }
    float wn0 = w0 / (d0 + EPS_SM), wn1 = w1 / (d1 + EPS_SM);
    float wn2 = w2 / (d2 + EPS_SM), wn3 = w3 / (d3 + EPS_SM);
    #pragma unroll 2
    for (int j = 0; j < deg; j++){
      int s = __shfl(mye, j);
      float wa = __shfl(wn0, j), wb = __shfl(wn1, j);
      float wc = __shfl(wn2, j), wd = __shfl(wn3, j);
      float w = hd == 0 ? wa : hd == 1 ? wb : hd == 2 ? wc : wd;
      ushort4 u = *(const ushort4*)(hb + (size_t)s * 256 + hd * 64 + cg);
      ax += __half2float(__ushort_as_half(u.x)) * w;
      ay += __half2float(__ushort_as_half(u.y)) * w;
      az += __half2float(__ushort_as_half(u.z)) * w;
      aw += __half2float(__ushort_as_half(u.w)) * w;
    }
  } else {
    float m0 = -1e30f, m1 = -1e30f, m2 = -1e30f, m3 = -1e30f;
    for (int i = beg + lane; i < end; i += 64){
      int s = csr[i];
      float4 av = *(const float4*)(al + (size_t)s * 4);
      m0 = fmaxf(m0, lrelu(av.x + arv.x));
      m1 = fmaxf(m1, lrelu(av.y + arv.y));
      m2 = fmaxf(m2, lrelu(av.z + arv.z));
      m3 = fmaxf(m3, lrelu(av.w + arv.w));
    }
    #pragma unroll
    for (int off = 32; off > 0; off >>= 1){
      m0 = fmaxf(m0, __shfl_xor(m0, off));
      m1 = fmaxf(m1, __shfl_xor(m1, off));
      m2 = fmaxf(m2, __shfl_xor(m2, off));
      m3 = fmaxf(m3, __shfl_xor(m3, off));
    }
    float d0 = 0.f, d1 = 0.f, d2 = 0.f, d3 = 0.f;
    for (int i = beg + lane; i < end; i += 64){
      int s = csr[i];
      float4 av = *(const float4*)(al + (size_t)s * 4);
      d0 += __expf(lrelu(av.x + arv.x) - m0);
      d1 += __expf(lrelu(av.y + arv.y) - m1);
      d2 += __expf(lrelu(av.z + arv.z) - m2);
      d3 += __expf(lrelu(av.w + arv.w) - m3);
    }
    #pragma unroll
    for (int off = 32; off > 0; off >>= 1){
      d0 += __shfl_xor(d0, off);
      d1 += __shfl_xor(d1, off);
      d2 += __shfl_xor(d2, off);
      d3 += __shfl_xor(d3, off);
    }
    float i0 = 1.f / (d0 + EPS_SM), i1 = 1.f / (d1 + EPS_SM);
    float i2 = 1.f / (d2 + EPS_SM), i3 = 1.f / (d3 + EPS_SM);
    float arh = hd == 0 ? arv.x : hd == 1 ? arv.y : hd == 2 ? arv.z : arv.w;
    float mh  = hd == 0 ? m0 : hd == 1 ? m1 : hd == 2 ? m2 : m3;
    float ih  = hd == 0 ? i0 : hd == 1 ? i1 : hd == 2 ? i2 : i3;
    for (int i = beg; i < end; i++){
      int s = csr[i];
      float w = __expf(lrelu(al[(size_t)s * 4 + hd] + arh) - mh) * ih;
      ushort4 u = *(const ushort4*)(hb + (size_t)s * 256 + hd * 64 + cg);
      ax += __half2float(__ushort_as_half(u.x)) * w;
      ay += __half2float(__ushort_as_half(u.y)) * w;
      az += __half2float(__ushort_as_half(u.z)) * w;
      aw += __half2float(__ushort_as_half(u.w)) * w;
    }
  }

  #pragma unroll
  for (int off = 16; off <= 32; off <<= 1){
    ax += __shfl_xor(ax, off);
    ay += __shfl_xor(ay, off);
    az += __shfl_xor(az, off);
    aw += __shfl_xor(aw, off);
  }
  if (lane < 16){
    float4 b4 = *(const float4*)(bias + cg);
    *(float4*)(out + (size_t)n * 64 + cg) =
        make_float4(ax * 0.25f + b4.x, ay * 0.25f + b4.y, az * 0.25f + b4.z, aw * 0.25f + b4.w);
  }
}

// ---------------- BatchNorm (training-mode stats) ----------------
__global__ __launch_bounds__(256) void k_bnstats(const float* __restrict__ x, int N,
                                                 float* __restrict__ gsum, float* __restrict__ gsq){
  int c = threadIdx.x & 63;
  int rg = threadIdx.x >> 6;  // 0..3
  float s = 0.f, q = 0.f;
  for (int r = blockIdx.x * 4 + rg; r < N; r += gridDim.x * 4){
    float v = x[(size_t)r * 64 + c];
    s += v; q += v * v;
  }
  __shared__ float ls[4][64], lq[4][64];
  ls[rg][c] = s; lq[rg][c] = q;
  __syncthreads();
  if (rg == 0){
    s = ls[0][c] + ls[1][c] + ls[2][c] + ls[3][c];
    q = lq[0][c] + lq[1][c] + lq[2][c] + lq[3][c];
    atomicAdd(&gsum[c], s);
    atomicAdd(&gsq[c], q);
  }
}

__global__ void k_bnfin(const float* __restrict__ gsum, const float* __restrict__ gsq,
                        float* __restrict__ mu, float* __restrict__ rstd, int N){
  int c = threadIdx.x;
  if (c < 64){
    float m = gsum[c] / (float)N;
    float v = gsq[c] / (float)N - m * m;
    mu[c] = m;
    rstd[c] = rsqrtf(v + EPS_BN);
  }
}

__global__ void k_bnapply(const float* __restrict__ x, const float* __restrict__ mu,
                          const float* __restrict__ rstd, const float* __restrict__ g,
                          const float* __restrict__ be, float* __restrict__ y, int total){
  int i = blockIdx.x * blockDim.x + threadIdx.x;
  if (i >= total) return;
  int c = i & 63;
  float v = (x[i] - mu[c]) * rstd[c] * g[c] + be[c];
  y[i] = fmaxf(v, 0.f);
}

// ---------------- launcher ----------------
extern "C" void kernel_launch(void* const* d_in, const int* in_sizes, int n_in,
                              void* d_out, int out_size, void* d_ws, size_t ws_size,
                              hipStream_t stream){
  const float* x  = (const float*)d_in[0];
  const int*   ei = (const int*)d_in[1];
  const float* W[3]  = {(const float*)d_in[2], (const float*)d_in[6],  (const float*)d_in[10]};
  const float* AS[3] = {(const float*)d_in[3], (const float*)d_in[7],  (const float*)d_in[11]};
  const float* AD[3] = {(const float*)d_in[4], (const float*)d_in[8],  (const float*)d_in[12]};
  const float* BI[3] = {(const float*)d_in[5], (const float*)d_in[9],  (const float*)d_in[13]};
  const float* G[2]  = {(const float*)d_in[14], (const float*)d_in[16]};
  const float* BE[2] = {(const float*)d_in[15], (const float*)d_in[17]};
  const int N = in_sizes[0] / 256;
  const int E = in_sizes[1] / 2;
  const int EN = E + N;

  char* wsb = (char*)d_ws;
  size_t off = 0;
  auto alloc = [&](size_t bytes) -> char* {
    char* p = wsb + off;
    off = (off + bytes + 255) & ~(size_t)255;
    return p;
  };
  int* cnt     = (int*)alloc((size_t)N * 4);
  int* cursor  = (int*)alloc((size_t)N * 4);
  int* rowptr  = (int*)alloc((size_t)(N + 1) * 4);
  int* part    = (int*)alloc(256 * 4);
  int* csr     = (int*)alloc((size_t)EN * 4);
  __half* hb   = (__half*)alloc((size_t)N * 256 * 2);
  float* al    = (float*)alloc((size_t)N * 4 * 4);
  float* ar    = (float*)alloc((size_t)N * 4 * 4);
  float* bufA  = (float*)alloc((size_t)N * 64 * 4);
  float* bufB  = (float*)alloc((size_t)N * 64 * 4);
  float* bn    = (float*)alloc(256 * 4);   // gsum0,gsq0,gsum1,gsq1
  float* murs  = (float*)alloc(128 * 4);   // mu, rstd

  const int chunk = (N + 255) / 256;  // 196 for N=50000; must be <= 256

  // CSR build (edge structure is static but ws is re-poisoned every call)
  k_zero_i32<<<(N + 255) / 256, 256, 0, stream>>>(cnt, N);
  k_zero_f32<<<1, 256, 0, stream>>>(bn, 256);
  k_count<<<(EN + 255) / 256, 256, 0, stream>>>(ei, E, N, cnt);
  k_blocksum<<<256, 256, 0, stream>>>(cnt, N, chunk, part);
  k_scanpart<<<1, 256, 0, stream>>>(part, rowptr, N);
  k_localscan<<<256, 256, 0, stream>>>(cnt, part, N, chunk, rowptr, cursor);
  k_fill<<<(EN + 255) / 256, 256, 0, stream>>>(ei, E, N, cursor, csr);

  const float* lin = x;
  for (int l = 0; l < 3; l++){
    int K = (l == 0) ? 256 : 64;
    dim3 gg((N + 63) / 64, 4);
    k_gemm<<<gg, 256, 0, stream>>>(lin, W[l], AS[l], AD[l], hb, al, ar, N, K);
    float* outp = (l == 2) ? (float*)d_out : bufA;
    k_node<<<(N + 3) / 4, 256, 0, stream>>>(rowptr, csr, hb, al, ar, BI[l], outp, N);
    if (l < 2){
      float* gsum = bn + l * 128;
      float* gsq  = gsum + 64;
      k_bnstats<<<128, 256, 0, stream>>>(bufA, N, gsum, gsq);
      k_bnfin<<<1, 64, 0, stream>>>(gsum, gsq, murs, murs + 64, N);
      k_bnapply<<<(N * 64 + 255) / 256, 256, 0, stream>>>(bufA, murs, murs + 64, G[l], BE[l], bufB, N * 64);
      lin = bufB;
    }
  }
}

// Round 4
// 619.414 us; speedup vs baseline: 1.6555x; 1.1213x over previous
//
#include <hip/hip_runtime.h>
#include <hip/hip_fp16.h>
#include <math.h>

constexpr float NEG_SLOPE = 0.2f;
constexpr float EPS_BN = 1e-5f;
constexpr float EPS_SM = 1e-16f;

typedef _Float16 half8 __attribute__((ext_vector_type(8)));
typedef _Float16 half4v __attribute__((ext_vector_type(4)));
typedef float f32x4 __attribute__((ext_vector_type(4)));

__device__ __forceinline__ float lrelu(float x){ return x >= 0.f ? x : NEG_SLOPE * x; }

// ---------------- utility ----------------
__global__ void k_zero_i32(int* p, int n){
  int i = blockIdx.x * blockDim.x + threadIdx.x;
  if (i < n) p[i] = 0;
}
__global__ void k_zero_f32(float* p, int n){
  int i = blockIdx.x * blockDim.x + threadIdx.x;
  if (i < n) p[i] = 0.f;
}

__global__ void k_x2h(const float* __restrict__ x, _Float16* __restrict__ xh, int total4){
  int t = blockIdx.x * blockDim.x + threadIdx.x;
  if (t >= total4) return;
  float4 v = ((const float4*)x)[t];
  half4v h = {(_Float16)v.x, (_Float16)v.y, (_Float16)v.z, (_Float16)v.w};
  *(half4v*)(xh + (size_t)t * 4) = h;
}

// Wt[n][k] = fp16(W[k][n]), n in [0,256)
__global__ void k_convW(const float* __restrict__ W, _Float16* __restrict__ Wt, int K){
  int t = blockIdx.x * blockDim.x + threadIdx.x;
  if (t >= K * 256) return;
  int n = t & 255, k = t >> 8;
  Wt[(size_t)n * K + k] = (_Float16)W[(size_t)k * 256 + n];
}

// ---------------- CSR build (dst -> list of src), incl. self loops ----------------
__global__ void k_count(const int* __restrict__ ei, int E, int N, int* __restrict__ cnt){
  int e = blockIdx.x * blockDim.x + threadIdx.x;
  if (e >= E + N) return;
  int dst = (e < E) ? ei[E + e] : (e - E);
  atomicAdd(&cnt[dst], 1);
}

__global__ __launch_bounds__(256) void k_blocksum(const int* __restrict__ cnt, int n, int chunk,
                                                  int* __restrict__ part){
  __shared__ int s[256];
  int b = blockIdx.x, t = threadIdx.x;
  int lo = b * chunk, hi = min(n, lo + chunk);
  int v = 0;
  for (int i = lo + t; i < hi; i += 256) v += cnt[i];
  s[t] = v;
  __syncthreads();
  #pragma unroll
  for (int off = 128; off > 0; off >>= 1){
    if (t < off) s[t] += s[t + off];
    __syncthreads();
  }
  if (t == 0) part[b] = s[0];
}

__global__ __launch_bounds__(256) void k_scanpart(int* __restrict__ part, int* __restrict__ ptr, int n){
  __shared__ int s[256];
  int t = threadIdx.x;
  int v = part[t];
  s[t] = v;
  __syncthreads();
  #pragma unroll
  for (int off = 1; off < 256; off <<= 1){
    int u = (t >= off) ? s[t - off] : 0;
    __syncthreads();
    s[t] += u;
    __syncthreads();
  }
  part[t] = s[t] - v;
  if (t == 255) ptr[n] = s[255];
}

__global__ __launch_bounds__(256) void k_localscan(const int* __restrict__ cnt, const int* __restrict__ part,
                                                   int n, int chunk, int* __restrict__ ptr,
                                                   int* __restrict__ cursor){
  __shared__ int s[256];
  int b = blockIdx.x, t = threadIdx.x;
  int i = b * chunk + t;
  int v = (t < chunk && i < n) ? cnt[i] : 0;
  s[t] = v;
  __syncthreads();
  #pragma unroll
  for (int off = 1; off < 256; off <<= 1){
    int u = (t >= off) ? s[t - off] : 0;
    __syncthreads();
    s[t] += u;
    __syncthreads();
  }
  if (t < chunk && i < n){
    int ex = part[b] + s[t] - v;
    ptr[i] = ex;
    cursor[i] = ex;
  }
}

__global__ void k_fill(const int* __restrict__ ei, int E, int N,
                       int* __restrict__ cursor, int* __restrict__ csr_src){
  int e = blockIdx.x * blockDim.x + threadIdx.x;
  if (e >= E + N) return;
  int src, dst;
  if (e < E){ src = ei[e]; dst = ei[E + e]; } else { src = e - E; dst = e - E; }
  int slot = atomicAdd(&cursor[dst], 1);
  csr_src[slot] = src;
}

// ---------------- MFMA GEMM (fp16 in, f32 acc) + attention coeffs + fp16 h ----------------
// Block: 128 rows x 64 cols (one head). 4 waves x (2 m-subtiles x 4 n-subtiles) of 16x16x32.
__global__ __launch_bounds__(256) void k_gemm(const _Float16* __restrict__ Xh,
    const _Float16* __restrict__ Wt, const float* __restrict__ a_s, const float* __restrict__ a_d,
    __half* __restrict__ hb, float* __restrict__ al, float* __restrict__ ar, int nrows, int K){
  // fragment-order LDS: [k-quad][row][8 halfs] -> every ds_read_b128 is lane-consecutive 16B
  __shared__ _Float16 Alds[4][128][8];  // 8 KB
  __shared__ _Float16 Blds[4][64][8];   // 4 KB
  int tid = threadIdx.x;
  int m0 = blockIdx.x * 128;
  int head = blockIdx.y;
  int n0 = head * 64;
  int w = tid >> 6, l = tid & 63;
  int lm = l & 15, lq = l >> 4;
  int qs = tid & 3, rs = tid >> 2;   // staging: k-quad, row/col index
  f32x4 acc[2][4] = {};

  for (int k0 = 0; k0 < K; k0 += 32){
    #pragma unroll
    for (int it = 0; it < 2; it++){
      int row = it * 64 + rs;
      int gr = m0 + row;
      half8 v = {};
      if (gr < nrows) v = *(const half8*)(Xh + (size_t)gr * K + k0 + qs * 8);
      *(half8*)&Alds[qs][row][0] = v;
    }
    *(half8*)&Blds[qs][rs][0] = *(const half8*)(Wt + (size_t)(n0 + rs) * K + k0 + qs * 8);
    __syncthreads();
    half8 af0 = *(const half8*)&Alds[lq][w * 32 + lm][0];
    half8 af1 = *(const half8*)&Alds[lq][w * 32 + 16 + lm][0];
    #pragma unroll
    for (int nt = 0; nt < 4; nt++){
      half8 bf = *(const half8*)&Blds[lq][nt * 16 + lm][0];
      acc[0][nt] = __builtin_amdgcn_mfma_f32_16x16x32_f16(af0, bf, acc[0][nt], 0, 0, 0);
      acc[1][nt] = __builtin_amdgcn_mfma_f32_16x16x32_f16(af1, bf, acc[1][nt], 0, 0, 0);
    }
    __syncthreads();
  }

  // epilogue: al/ar (reduce over the 64 cols of this head) + fp16 h store
  float asv[4], adv[4];
  #pragma unroll
  for (int nt = 0; nt < 4; nt++){
    asv[nt] = a_s[n0 + nt * 16 + lm];
    adv[nt] = a_d[n0 + nt * 16 + lm];
  }
  #pragma unroll
  for (int s = 0; s < 2; s++){
    #pragma unroll
    for (int reg = 0; reg < 4; reg++){
      float sl = 0.f, sr = 0.f;
      #pragma unroll
      for (int nt = 0; nt < 4; nt++){
        sl += acc[s][nt][reg] * asv[nt];
        sr += acc[s][nt][reg] * adv[nt];
      }
      #pragma unroll
      for (int off = 1; off < 16; off <<= 1){
        sl += __shfl_xor(sl, off);
        sr += __shfl_xor(sr, off);
      }
      int grow = m0 + w * 32 + s * 16 + lq * 4 + reg;
      if (lm == 0 && grow < nrows){
        al[(size_t)grow * 4 + head] = sl;
        ar[(size_t)grow * 4 + head] = sr;
      }
    }
  }
  #pragma unroll
  for (int s = 0; s < 2; s++){
    #pragma unroll
    for (int nt = 0; nt < 4; nt++){
      #pragma unroll
      for (int reg = 0; reg < 4; reg++){
        int grow = m0 + w * 32 + s * 16 + lq * 4 + reg;
        if (grow < nrows)
          hb[(size_t)grow * 256 + n0 + nt * 16 + lm] = __float2half(acc[s][nt][reg]);
      }
    }
  }
}

// ---------------- per-node softmax + aggregate (wave per node) ----------------
__global__ __launch_bounds__(256) void k_node(const int* __restrict__ ptr,
    const int* __restrict__ csr, const __half* __restrict__ hb,
    const float* __restrict__ al, const float* __restrict__ ar,
    const float* __restrict__ bias, float* __restrict__ out, int N){
  int n = (blockIdx.x * blockDim.x + threadIdx.x) >> 6;
  int lane = threadIdx.x & 63;
  if (n >= N) return;
  int beg = ptr[n], end = ptr[n + 1];
  int deg = end - beg;
  float4 arv = *(const float4*)(ar + (size_t)n * 4);
  int hd = lane >> 4;
  int cg = (lane & 15) * 4;
  float ax = 0.f, ay = 0.f, az = 0.f, aw = 0.f;

  if (deg <= 64){
    int idx = beg + lane;
    bool act = idx < end;
    int mye = act ? csr[idx] : 0;
    float e0 = -1e30f, e1 = -1e30f, e2 = -1e30f, e3 = -1e30f;
    if (act){
      float4 av = *(const float4*)(al + (size_t)mye * 4);
      e0 = lrelu(av.x + arv.x); e1 = lrelu(av.y + arv.y);
      e2 = lrelu(av.z + arv.z); e3 = lrelu(av.w + arv.w);
    }
    float m0 = e0, m1 = e1, m2 = e2, m3 = e3;
    #pragma unroll
    for (int off = 32; off > 0; off >>= 1){
      m0 = fmaxf(m0, __shfl_xor(m0, off));
      m1 = fmaxf(m1, __shfl_xor(m1, off));
      m2 = fmaxf(m2, __shfl_xor(m2, off));
      m3 = fmaxf(m3, __shfl_xor(m3, off));
    }
    float w0 = __expf(e0 - m0), w1 = __expf(e1 - m1);
    float w2 = __expf(e2 - m2), w3 = __expf(e3 - m3);
    float d0 = w0, d1 = w1, d2 = w2, d3 = w3;
    #pragma unroll
    for (int off = 32; off > 0; off >>= 1){
      d0 += __shfl_xor(d0, off);
      d1 += __shfl_xor(d1, off);
      d2 += __shfl_xor(d2, off);
      d3 += __shfl_xor(d3, off);
    }
    float wn0 = w0 / (d0 + EPS_SM), wn1 = w1 / (d1 + EPS_SM);
    float wn2 = w2 / (d2 + EPS_SM), wn3 = w3 / (d3 + EPS_SM);
    #pragma unroll 2
    for (int j = 0; j < deg; j++){
      int s = __shfl(mye, j);
      float wa = __shfl(wn0, j), wb = __shfl(wn1, j);
      float wc = __shfl(wn2, j), wd = __shfl(wn3, j);
      float w = hd == 0 ? wa : hd == 1 ? wb : hd == 2 ? wc : wd;
      ushort4 u = *(const ushort4*)(hb + (size_t)s * 256 + hd * 64 + cg);
      ax += __half2float(__ushort_as_half(u.x)) * w;
      ay += __half2float(__ushort_as_half(u.y)) * w;
      az += __half2float(__ushort_as_half(u.z)) * w;
      aw += __half2float(__ushort_as_half(u.w)) * w;
    }
  } else {
    float m0 = -1e30f, m1 = -1e30f, m2 = -1e30f, m3 = -1e30f;
    for (int i = beg + lane; i < end; i += 64){
      int s = csr[i];
      float4 av = *(const float4*)(al + (size_t)s * 4);
      m0 = fmaxf(m0, lrelu(av.x + arv.x));
      m1 = fmaxf(m1, lrelu(av.y + arv.y));
      m2 = fmaxf(m2, lrelu(av.z + arv.z));
      m3 = fmaxf(m3, lrelu(av.w + arv.w));
    }
    #pragma unroll
    for (int off = 32; off > 0; off >>= 1){
      m0 = fmaxf(m0, __shfl_xor(m0, off));
      m1 = fmaxf(m1, __shfl_xor(m1, off));
      m2 = fmaxf(m2, __shfl_xor(m2, off));
      m3 = fmaxf(m3, __shfl_xor(m3, off));
    }
    float d0 = 0.f, d1 = 0.f, d2 = 0.f, d3 = 0.f;
    for (int i = beg + lane; i < end; i += 64){
      int s = csr[i];
      float4 av = *(const float4*)(al + (size_t)s * 4);
      d0 += __expf(lrelu(av.x + arv.x) - m0);
      d1 += __expf(lrelu(av.y + arv.y) - m1);
      d2 += __expf(lrelu(av.z + arv.z) - m2);
      d3 += __expf(lrelu(av.w + arv.w) - m3);
    }
    #pragma unroll
    for (int off = 32; off > 0; off >>= 1){
      d0 += __shfl_xor(d0, off);
      d1 += __shfl_xor(d1, off);
      d2 += __shfl_xor(d2, off);
      d3 += __shfl_xor(d3, off);
    }
    float i0 = 1.f / (d0 + EPS_SM), i1 = 1.f / (d1 + EPS_SM);
    float i2 = 1.f / (d2 + EPS_SM), i3 = 1.f / (d3 + EPS_SM);
    float arh = hd == 0 ? arv.x : hd == 1 ? arv.y : hd == 2 ? arv.z : arv.w;
    float mh  = hd == 0 ? m0 : hd == 1 ? m1 : hd == 2 ? m2 : m3;
    float ih  = hd == 0 ? i0 : hd == 1 ? i1 : hd == 2 ? i2 : i3;
    for (int i = beg; i < end; i++){
      int s = csr[i];
      float w = __expf(lrelu(al[(size_t)s * 4 + hd] + arh) - mh) * ih;
      ushort4 u = *(const ushort4*)(hb + (size_t)s * 256 + hd * 64 + cg);
      ax += __half2float(__ushort_as_half(u.x)) * w;
      ay += __half2float(__ushort_as_half(u.y)) * w;
      az += __half2float(__ushort_as_half(u.z)) * w;
      aw += __half2float(__ushort_as_half(u.w)) * w;
    }
  }

  #pragma unroll
  for (int off = 16; off <= 32; off <<= 1){
    ax += __shfl_xor(ax, off);
    ay += __shfl_xor(ay, off);
    az += __shfl_xor(az, off);
    aw += __shfl_xor(aw, off);
  }
  if (lane < 16){
    float4 b4 = *(const float4*)(bias + cg);
    *(float4*)(out + (size_t)n * 64 + cg) =
        make_float4(ax * 0.25f + b4.x, ay * 0.25f + b4.y, az * 0.25f + b4.z, aw * 0.25f + b4.w);
  }
}

// ---------------- BatchNorm (training-mode stats) ----------------
__global__ __launch_bounds__(256) void k_bnstats(const float* __restrict__ x, int N,
                                                 float* __restrict__ gsum, float* __restrict__ gsq){
  int c = threadIdx.x & 63;
  int rg = threadIdx.x >> 6;
  float s = 0.f, q = 0.f;
  for (int r = blockIdx.x * 4 + rg; r < N; r += gridDim.x * 4){
    float v = x[(size_t)r * 64 + c];
    s += v; q += v * v;
  }
  __shared__ float ls[4][64], lq[4][64];
  ls[rg][c] = s; lq[rg][c] = q;
  __syncthreads();
  if (rg == 0){
    s = ls[0][c] + ls[1][c] + ls[2][c] + ls[3][c];
    q = lq[0][c] + lq[1][c] + lq[2][c] + lq[3][c];
    atomicAdd(&gsum[c], s);
    atomicAdd(&gsq[c], q);
  }
}

__global__ void k_bnfin(const float* __restrict__ gsum, const float* __restrict__ gsq,
                        float* __restrict__ mu, float* __restrict__ rstd, int N){
  int c = threadIdx.x;
  if (c < 64){
    float m = gsum[c] / (float)N;
    float v = gsq[c] / (float)N - m * m;
    mu[c] = m;
    rstd[c] = rsqrtf(v + EPS_BN);
  }
}

// normalize + ReLU, write fp16 (next layer's GEMM input)
__global__ void k_bnapply(const float* __restrict__ x, const float* __restrict__ mu,
                          const float* __restrict__ rstd, const float* __restrict__ g,
                          const float* __restrict__ be, _Float16* __restrict__ y, int total){
  int i = blockIdx.x * blockDim.x + threadIdx.x;
  if (i >= total) return;
  int c = i & 63;
  float v = (x[i] - mu[c]) * rstd[c] * g[c] + be[c];
  y[i] = (_Float16)fmaxf(v, 0.f);
}

// ---------------- launcher ----------------
extern "C" void kernel_launch(void* const* d_in, const int* in_sizes, int n_in,
                              void* d_out, int out_size, void* d_ws, size_t ws_size,
                              hipStream_t stream){
  const float* x  = (const float*)d_in[0];
  const int*   ei = (const int*)d_in[1];
  const float* W[3]  = {(const float*)d_in[2], (const float*)d_in[6],  (const float*)d_in[10]};
  const float* AS[3] = {(const float*)d_in[3], (const float*)d_in[7],  (const float*)d_in[11]};
  const float* AD[3] = {(const float*)d_in[4], (const float*)d_in[8],  (const float*)d_in[12]};
  const float* BI[3] = {(const float*)d_in[5], (const float*)d_in[9],  (const float*)d_in[13]};
  const float* G[2]  = {(const float*)d_in[14], (const float*)d_in[16]};
  const float* BE[2] = {(const float*)d_in[15], (const float*)d_in[17]};
  const int N = in_sizes[0] / 256;
  const int E = in_sizes[1] / 2;
  const int EN = E + N;

  char* wsb = (char*)d_ws;
  size_t off = 0;
  auto alloc = [&](size_t bytes) -> char* {
    char* p = wsb + off;
    off = (off + bytes + 255) & ~(size_t)255;
    return p;
  };
  int* cnt      = (int*)alloc((size_t)N * 4);
  int* cursor   = (int*)alloc((size_t)N * 4);
  int* rowptr   = (int*)alloc((size_t)(N + 1) * 4);
  int* part     = (int*)alloc(256 * 4);
  int* csr      = (int*)alloc((size_t)EN * 4);
  _Float16* xh0 = (_Float16*)alloc((size_t)N * 256 * 2);
  _Float16* Wt  = (_Float16*)alloc((size_t)256 * 256 * 2);
  __half* hb    = (__half*)alloc((size_t)N * 256 * 2);
  float* al     = (float*)alloc((size_t)N * 4 * 4);
  float* ar     = (float*)alloc((size_t)N * 4 * 4);
  float* bufA   = (float*)alloc((size_t)N * 64 * 4);
  _Float16* bufH= (_Float16*)alloc((size_t)N * 64 * 2);
  float* bn     = (float*)alloc(256 * 4);
  float* murs   = (float*)alloc(128 * 4);

  const int chunk = (N + 255) / 256;

  k_zero_i32<<<(N + 255) / 256, 256, 0, stream>>>(cnt, N);
  k_zero_f32<<<1, 256, 0, stream>>>(bn, 256);
  k_count<<<(EN + 255) / 256, 256, 0, stream>>>(ei, E, N, cnt);
  k_blocksum<<<256, 256, 0, stream>>>(cnt, N, chunk, part);
  k_scanpart<<<1, 256, 0, stream>>>(part, rowptr, N);
  k_localscan<<<256, 256, 0, stream>>>(cnt, part, N, chunk, rowptr, cursor);
  k_fill<<<(EN + 255) / 256, 256, 0, stream>>>(ei, E, N, cursor, csr);
  k_x2h<<<(N * 64 + 255) / 256, 256, 0, stream>>>(x, xh0, N * 64);  // N*256/4 elems of float4

  const _Float16* lin = xh0;
  for (int l = 0; l < 3; l++){
    int K = (l == 0) ? 256 : 64;
    k_convW<<<(K * 256 + 255) / 256, 256, 0, stream>>>(W[l], Wt, K);
    dim3 gg((N + 127) / 128, 4);
    k_gemm<<<gg, 256, 0, stream>>>(lin, Wt, AS[l], AD[l], hb, al, ar, N, K);
    float* outp = (l == 2) ? (float*)d_out : bufA;
    k_node<<<(N + 3) / 4, 256, 0, stream>>>(rowptr, csr, hb, al, ar, BI[l], outp, N);
    if (l < 2){
      float* gsum = bn + l * 128;
      float* gsq  = gsum + 64;
      k_bnstats<<<128, 256, 0, stream>>>(bufA, N, gsum, gsq);
      k_bnfin<<<1, 64, 0, stream>>>(gsum, gsq, murs, murs + 64, N);
      k_bnapply<<<(N * 64 + 255) / 256, 256, 0, stream>>>(bufA, murs, murs + 64, G[l], BE[l], bufH, N * 64);
      lin = bufH;
    }
  }
}

// Round 5
// 570.446 us; speedup vs baseline: 1.7976x; 1.0858x over previous
//
#include <hip/hip_runtime.h>
#include <hip/hip_fp16.h>
#include <math.h>

constexpr float NEG_SLOPE = 0.2f;
constexpr float EPS_BN = 1e-5f;
constexpr float EPS_SM = 1e-16f;

typedef _Float16 half8 __attribute__((ext_vector_type(8)));
typedef _Float16 half4v __attribute__((ext_vector_type(4)));
typedef float f32x4 __attribute__((ext_vector_type(4)));

__device__ __forceinline__ float lrelu(float x){ return x >= 0.f ? x : NEG_SLOPE * x; }

// ---------------- utility ----------------
__global__ void k_init(int* cnt, int n, float* bn, int* tick){
  int i = blockIdx.x * blockDim.x + threadIdx.x;
  if (i < n) cnt[i] = 0;
  if (i < 256) bn[i] = 0.f;
  if (i < 4) tick[i] = 0;
}

__global__ void k_x2h(const float* __restrict__ x, _Float16* __restrict__ xh, int total4){
  int t = blockIdx.x * blockDim.x + threadIdx.x;
  if (t >= total4) return;
  float4 v = ((const float4*)x)[t];
  half4v h = {(_Float16)v.x, (_Float16)v.y, (_Float16)v.z, (_Float16)v.w};
  *(half4v*)(xh + (size_t)t * 4) = h;
}

// Wt[n][k] = fp16(W[k][n]), n in [0,256)
__global__ void k_convW(const float* __restrict__ W, _Float16* __restrict__ Wt, int K){
  int t = blockIdx.x * blockDim.x + threadIdx.x;
  if (t >= K * 256) return;
  int n = t & 255, k = t >> 8;
  Wt[(size_t)n * K + k] = (_Float16)W[(size_t)k * 256 + n];
}

// ---------------- CSR build (dst -> list of src), incl. self loops ----------------
__global__ void k_count(const int* __restrict__ ei, int E, int N, int* __restrict__ cnt){
  int e = blockIdx.x * blockDim.x + threadIdx.x;
  if (e >= E + N) return;
  int dst = (e < E) ? ei[E + e] : (e - E);
  atomicAdd(&cnt[dst], 1);
}

__global__ __launch_bounds__(256) void k_blocksum(const int* __restrict__ cnt, int n, int chunk,
                                                  int* __restrict__ part){
  __shared__ int s[256];
  int b = blockIdx.x, t = threadIdx.x;
  int lo = b * chunk, hi = min(n, lo + chunk);
  int v = 0;
  for (int i = lo + t; i < hi; i += 256) v += cnt[i];
  s[t] = v;
  __syncthreads();
  #pragma unroll
  for (int off = 128; off > 0; off >>= 1){
    if (t < off) s[t] += s[t + off];
    __syncthreads();
  }
  if (t == 0) part[b] = s[0];
}

__global__ __launch_bounds__(256) void k_scanpart(int* __restrict__ part, int* __restrict__ ptr, int n){
  __shared__ int s[256];
  int t = threadIdx.x;
  int v = part[t];
  s[t] = v;
  __syncthreads();
  #pragma unroll
  for (int off = 1; off < 256; off <<= 1){
    int u = (t >= off) ? s[t - off] : 0;
    __syncthreads();
    s[t] += u;
    __syncthreads();
  }
  part[t] = s[t] - v;
  if (t == 255) ptr[n] = s[255];
}

__global__ __launch_bounds__(256) void k_localscan(const int* __restrict__ cnt, const int* __restrict__ part,
                                                   int n, int chunk, int* __restrict__ ptr,
                                                   int* __restrict__ cursor){
  __shared__ int s[256];
  int b = blockIdx.x, t = threadIdx.x;
  int i = b * chunk + t;
  int v = (t < chunk && i < n) ? cnt[i] : 0;
  s[t] = v;
  __syncthreads();
  #pragma unroll
  for (int off = 1; off < 256; off <<= 1){
    int u = (t >= off) ? s[t - off] : 0;
    __syncthreads();
    s[t] += u;
    __syncthreads();
  }
  if (t < chunk && i < n){
    int ex = part[b] + s[t] - v;
    ptr[i] = ex;
    cursor[i] = ex;
  }
}

__global__ void k_fill(const int* __restrict__ ei, int E, int N,
                       int* __restrict__ cursor, int* __restrict__ csr_src){
  int e = blockIdx.x * blockDim.x + threadIdx.x;
  if (e >= E + N) return;
  int src, dst;
  if (e < E){ src = ei[e]; dst = ei[E + e]; } else { src = e - E; dst = e - E; }
  int slot = atomicAdd(&cursor[dst], 1);
  csr_src[slot] = src;
}

// ---------------- MFMA GEMM (fp16 in, f32 acc) + attention coeffs + fp16 h ----------------
__global__ __launch_bounds__(256) void k_gemm(const _Float16* __restrict__ Xh,
    const _Float16* __restrict__ Wt, const float* __restrict__ a_s, const float* __restrict__ a_d,
    __half* __restrict__ hb, float* __restrict__ al, float* __restrict__ ar, int nrows, int K){
  __shared__ _Float16 Alds[4][128][8];  // 8 KB
  __shared__ _Float16 Blds[4][64][8];   // 4 KB
  int tid = threadIdx.x;
  int m0 = blockIdx.x * 128;
  int head = blockIdx.y;
  int n0 = head * 64;
  int w = tid >> 6, l = tid & 63;
  int lm = l & 15, lq = l >> 4;
  int qs = tid & 3, rs = tid >> 2;
  f32x4 acc[2][4] = {};

  for (int k0 = 0; k0 < K; k0 += 32){
    #pragma unroll
    for (int it = 0; it < 2; it++){
      int row = it * 64 + rs;
      int gr = m0 + row;
      half8 v = {};
      if (gr < nrows) v = *(const half8*)(Xh + (size_t)gr * K + k0 + qs * 8);
      *(half8*)&Alds[qs][row][0] = v;
    }
    *(half8*)&Blds[qs][rs][0] = *(const half8*)(Wt + (size_t)(n0 + rs) * K + k0 + qs * 8);
    __syncthreads();
    half8 af0 = *(const half8*)&Alds[lq][w * 32 + lm][0];
    half8 af1 = *(const half8*)&Alds[lq][w * 32 + 16 + lm][0];
    #pragma unroll
    for (int nt = 0; nt < 4; nt++){
      half8 bf = *(const half8*)&Blds[lq][nt * 16 + lm][0];
      acc[0][nt] = __builtin_amdgcn_mfma_f32_16x16x32_f16(af0, bf, acc[0][nt], 0, 0, 0);
      acc[1][nt] = __builtin_amdgcn_mfma_f32_16x16x32_f16(af1, bf, acc[1][nt], 0, 0, 0);
    }
    __syncthreads();
  }

  float asv[4], adv[4];
  #pragma unroll
  for (int nt = 0; nt < 4; nt++){
    asv[nt] = a_s[n0 + nt * 16 + lm];
    adv[nt] = a_d[n0 + nt * 16 + lm];
  }
  #pragma unroll
  for (int s = 0; s < 2; s++){
    #pragma unroll
    for (int reg = 0; reg < 4; reg++){
      float sl = 0.f, sr = 0.f;
      #pragma unroll
      for (int nt = 0; nt < 4; nt++){
        sl += acc[s][nt][reg] * asv[nt];
        sr += acc[s][nt][reg] * adv[nt];
      }
      #pragma unroll
      for (int off = 1; off < 16; off <<= 1){
        sl += __shfl_xor(sl, off);
        sr += __shfl_xor(sr, off);
      }
      int grow = m0 + w * 32 + s * 16 + lq * 4 + reg;
      if (lm == 0 && grow < nrows){
        al[(size_t)grow * 4 + head] = sl;
        ar[(size_t)grow * 4 + head] = sr;
      }
    }
  }
  #pragma unroll
  for (int s = 0; s < 2; s++){
    #pragma unroll
    for (int nt = 0; nt < 4; nt++){
      #pragma unroll
      for (int reg = 0; reg < 4; reg++){
        int grow = m0 + w * 32 + s * 16 + lq * 4 + reg;
        if (grow < nrows)
          hb[(size_t)grow * 256 + n0 + nt * 16 + lm] = __float2half(acc[s][nt][reg]);
      }
    }
  }
}

// ---------------- per-node softmax + aggregate (wave per node) ----------------
__global__ __launch_bounds__(256) void k_node(const int* __restrict__ ptr,
    const int* __restrict__ csr, const __half* __restrict__ hb,
    const float* __restrict__ al, const float* __restrict__ ar,
    const float* __restrict__ bias, float* __restrict__ out, int N){
  __shared__ float4 wsm[4][64];   // per-wave: normalized weights per edge (4 heads)
  __shared__ int    ssm[4][64];   // per-wave: src index per edge
  int n = (blockIdx.x * blockDim.x + threadIdx.x) >> 6;
  int lane = threadIdx.x & 63;
  int wv = threadIdx.x >> 6;
  if (n >= N) return;
  int beg = ptr[n], end = ptr[n + 1];
  int deg = end - beg;
  float4 arv = *(const float4*)(ar + (size_t)n * 4);
  int hd = lane >> 4;
  int cg = (lane & 15) * 4;
  float ax = 0.f, ay = 0.f, az = 0.f, aw = 0.f;

  if (deg <= 64){
    int idx = beg + lane;
    bool act = idx < end;
    int mye = act ? csr[idx] : 0;
    float e0 = -1e30f, e1 = -1e30f, e2 = -1e30f, e3 = -1e30f;
    if (act){
      float4 av = *(const float4*)(al + (size_t)mye * 4);
      e0 = lrelu(av.x + arv.x); e1 = lrelu(av.y + arv.y);
      e2 = lrelu(av.z + arv.z); e3 = lrelu(av.w + arv.w);
    }
    float m0 = e0, m1 = e1, m2 = e2, m3 = e3;
    #pragma unroll
    for (int off = 32; off > 0; off >>= 1){
      m0 = fmaxf(m0, __shfl_xor(m0, off));
      m1 = fmaxf(m1, __shfl_xor(m1, off));
      m2 = fmaxf(m2, __shfl_xor(m2, off));
      m3 = fmaxf(m3, __shfl_xor(m3, off));
    }
    float w0 = __expf(e0 - m0), w1 = __expf(e1 - m1);
    float w2 = __expf(e2 - m2), w3 = __expf(e3 - m3);
    float d0 = w0, d1 = w1, d2 = w2, d3 = w3;
    #pragma unroll
    for (int off = 32; off > 0; off >>= 1){
      d0 += __shfl_xor(d0, off);
      d1 += __shfl_xor(d1, off);
      d2 += __shfl_xor(d2, off);
      d3 += __shfl_xor(d3, off);
    }
    // stage per-edge {src, weights} in LDS (lane j owns edge j); wave-local
    wsm[wv][lane] = make_float4(w0 / (d0 + EPS_SM), w1 / (d1 + EPS_SM),
                                w2 / (d2 + EPS_SM), w3 / (d3 + EPS_SM));
    ssm[wv][lane] = mye;
    __builtin_amdgcn_wave_barrier();   // compiler fence; HW wave is lockstep
    const float* wbase = (const float*)&wsm[wv][0];
    #pragma unroll 2
    for (int j = 0; j < deg; j++){
      int s = ssm[wv][j];                 // broadcast ds_read
      float w = wbase[j * 4 + hd];        // 4-addr multicast ds_read
      ushort4 u = *(const ushort4*)(hb + (size_t)s * 256 + hd * 64 + cg);
      ax += __half2float(__ushort_as_half(u.x)) * w;
      ay += __half2float(__ushort_as_half(u.y)) * w;
      az += __half2float(__ushort_as_half(u.z)) * w;
      aw += __half2float(__ushort_as_half(u.w)) * w;
    }
  } else {
    float m0 = -1e30f, m1 = -1e30f, m2 = -1e30f, m3 = -1e30f;
    for (int i = beg + lane; i < end; i += 64){
      int s = csr[i];
      float4 av = *(const float4*)(al + (size_t)s * 4);
      m0 = fmaxf(m0, lrelu(av.x + arv.x));
      m1 = fmaxf(m1, lrelu(av.y + arv.y));
      m2 = fmaxf(m2, lrelu(av.z + arv.z));
      m3 = fmaxf(m3, lrelu(av.w + arv.w));
    }
    #pragma unroll
    for (int off = 32; off > 0; off >>= 1){
      m0 = fmaxf(m0, __shfl_xor(m0, off));
      m1 = fmaxf(m1, __shfl_xor(m1, off));
      m2 = fmaxf(m2, __shfl_xor(m2, off));
      m3 = fmaxf(m3, __shfl_xor(m3, off));
    }
    float d0 = 0.f, d1 = 0.f, d2 = 0.f, d3 = 0.f;
    for (int i = beg + lane; i < end; i += 64){
      int s = csr[i];
      float4 av = *(const float4*)(al + (size_t)s * 4);
      d0 += __expf(lrelu(av.x + arv.x) - m0);
      d1 += __expf(lrelu(av.y + arv.y) - m1);
      d2 += __expf(lrelu(av.z + arv.z) - m2);
      d3 += __expf(lrelu(av.w + arv.w) - m3);
    }
    #pragma unroll
    for (int off = 32; off > 0; off >>= 1){
      d0 += __shfl_xor(d0, off);
      d1 += __shfl_xor(d1, off);
      d2 += __shfl_xor(d2, off);
      d3 += __shfl_xor(d3, off);
    }
    float i0 = 1.f / (d0 + EPS_SM), i1 = 1.f / (d1 + EPS_SM);
    float i2 = 1.f / (d2 + EPS_SM), i3 = 1.f / (d3 + EPS_SM);
    float arh = hd == 0 ? arv.x : hd == 1 ? arv.y : hd == 2 ? arv.z : arv.w;
    float mh  = hd == 0 ? m0 : hd == 1 ? m1 : hd == 2 ? m2 : m3;
    float ih  = hd == 0 ? i0 : hd == 1 ? i1 : hd == 2 ? i2 : i3;
    for (int i = beg; i < end; i++){
      int s = csr[i];
      float w = __expf(lrelu(al[(size_t)s * 4 + hd] + arh) - mh) * ih;
      ushort4 u = *(const ushort4*)(hb + (size_t)s * 256 + hd * 64 + cg);
      ax += __half2float(__ushort_as_half(u.x)) * w;
      ay += __half2float(__ushort_as_half(u.y)) * w;
      az += __half2float(__ushort_as_half(u.z)) * w;
      aw += __half2float(__ushort_as_half(u.w)) * w;
    }
  }

  #pragma unroll
  for (int off = 16; off <= 32; off <<= 1){
    ax += __shfl_xor(ax, off);
    ay += __shfl_xor(ay, off);
    az += __shfl_xor(az, off);
    aw += __shfl_xor(aw, off);
  }
  if (lane < 16){
    float4 b4 = *(const float4*)(bias + cg);
    *(float4*)(out + (size_t)n * 64 + cg) =
        make_float4(ax * 0.25f + b4.x, ay * 0.25f + b4.y, az * 0.25f + b4.z, aw * 0.25f + b4.w);
  }
}

// ---------------- BatchNorm stats + fused finalize (last-block pattern) ----------------
__global__ __launch_bounds__(256) void k_bnstats(const float* __restrict__ x, int N,
                                                 float* __restrict__ gsum, float* __restrict__ gsq,
                                                 int* __restrict__ tick,
                                                 float* __restrict__ mu, float* __restrict__ rstd){
  int c = threadIdx.x & 63;
  int rg = threadIdx.x >> 6;
  float s = 0.f, q = 0.f;
  for (int r = blockIdx.x * 4 + rg; r < N; r += gridDim.x * 4){
    float v = x[(size_t)r * 64 + c];
    s += v; q += v * v;
  }
  __shared__ float ls[4][64], lq[4][64];
  __shared__ int amLast;
  ls[rg][c] = s; lq[rg][c] = q;
  __syncthreads();
  if (rg == 0){
    s = ls[0][c] + ls[1][c] + ls[2][c] + ls[3][c];
    q = lq[0][c] + lq[1][c] + lq[2][c] + lq[3][c];
    atomicAdd(&gsum[c], s);
    atomicAdd(&gsq[c], q);
  }
  __threadfence();
  if (threadIdx.x == 0)
    amLast = (atomicAdd(tick, 1) == (int)gridDim.x - 1) ? 1 : 0;
  __syncthreads();
  if (amLast && threadIdx.x < 64){
    float gs = atomicAdd(&gsum[c], 0.f);   // coherent read
    float gq = atomicAdd(&gsq[c], 0.f);
    float m = gs / (float)N;
    float v = gq / (float)N - m * m;
    mu[c] = m;
    rstd[c] = rsqrtf(v + EPS_BN);
  }
}

// normalize + ReLU, write fp16 (next layer's GEMM input)
__global__ void k_bnapply(const float* __restrict__ x, const float* __restrict__ mu,
                          const float* __restrict__ rstd, const float* __restrict__ g,
                          const float* __restrict__ be, _Float16* __restrict__ y, int total){
  int i = blockIdx.x * blockDim.x + threadIdx.x;
  if (i >= total) return;
  int c = i & 63;
  float v = (x[i] - mu[c]) * rstd[c] * g[c] + be[c];
  y[i] = (_Float16)fmaxf(v, 0.f);
}

// ---------------- launcher ----------------
extern "C" void kernel_launch(void* const* d_in, const int* in_sizes, int n_in,
                              void* d_out, int out_size, void* d_ws, size_t ws_size,
                              hipStream_t stream){
  const float* x  = (const float*)d_in[0];
  const int*   ei = (const int*)d_in[1];
  const float* W[3]  = {(const float*)d_in[2], (const float*)d_in[6],  (const float*)d_in[10]};
  const float* AS[3] = {(const float*)d_in[3], (const float*)d_in[7],  (const float*)d_in[11]};
  const float* AD[3] = {(const float*)d_in[4], (const float*)d_in[8],  (const float*)d_in[12]};
  const float* BI[3] = {(const float*)d_in[5], (const float*)d_in[9],  (const float*)d_in[13]};
  const float* G[2]  = {(const float*)d_in[14], (const float*)d_in[16]};
  const float* BE[2] = {(const float*)d_in[15], (const float*)d_in[17]};
  const int N = in_sizes[0] / 256;
  const int E = in_sizes[1] / 2;
  const int EN = E + N;

  char* wsb = (char*)d_ws;
  size_t off = 0;
  auto alloc = [&](size_t bytes) -> char* {
    char* p = wsb + off;
    off = (off + bytes + 255) & ~(size_t)255;
    return p;
  };
  int* cnt      = (int*)alloc((size_t)N * 4);
  int* cursor   = (int*)alloc((size_t)N * 4);
  int* rowptr   = (int*)alloc((size_t)(N + 1) * 4);
  int* part     = (int*)alloc(256 * 4);
  int* csr      = (int*)alloc((size_t)EN * 4);
  _Float16* xh0 = (_Float16*)alloc((size_t)N * 256 * 2);
  _Float16* Wt  = (_Float16*)alloc((size_t)256 * 256 * 2);
  __half* hb    = (__half*)alloc((size_t)N * 256 * 2);
  float* al     = (float*)alloc((size_t)N * 4 * 4);
  float* ar     = (float*)alloc((size_t)N * 4 * 4);
  float* bufA   = (float*)alloc((size_t)N * 64 * 4);
  _Float16* bufH= (_Float16*)alloc((size_t)N * 64 * 2);
  float* bn     = (float*)alloc(256 * 4);
  int*   tick   = (int*)alloc(4 * 4);
  float* murs   = (float*)alloc(128 * 4);

  const int chunk = (N + 255) / 256;

  k_init<<<(N + 255) / 256, 256, 0, stream>>>(cnt, N, bn, tick);
  k_count<<<(EN + 255) / 256, 256, 0, stream>>>(ei, E, N, cnt);
  k_blocksum<<<256, 256, 0, stream>>>(cnt, N, chunk, part);
  k_scanpart<<<1, 256, 0, stream>>>(part, rowptr, N);
  k_localscan<<<256, 256, 0, stream>>>(cnt, part, N, chunk, rowptr, cursor);
  k_fill<<<(EN + 255) / 256, 256, 0, stream>>>(ei, E, N, cursor, csr);
  k_x2h<<<(N * 64 + 255) / 256, 256, 0, stream>>>(x, xh0, N * 64);

  const _Float16* lin = xh0;
  for (int l = 0; l < 3; l++){
    int K = (l == 0) ? 256 : 64;
    k_convW<<<(K * 256 + 255) / 256, 256, 0, stream>>>(W[l], Wt, K);
    dim3 gg((N + 127) / 128, 4);
    k_gemm<<<gg, 256, 0, stream>>>(lin, Wt, AS[l], AD[l], hb, al, ar, N, K);
    float* outp = (l == 2) ? (float*)d_out : bufA;
    k_node<<<(N + 3) / 4, 256, 0, stream>>>(rowptr, csr, hb, al, ar, BI[l], outp, N);
    if (l < 2){
      float* gsum = bn + l * 128;
      float* gsq  = gsum + 64;
      k_bnstats<<<128, 256, 0, stream>>>(bufA, N, gsum, gsq, tick + l, murs, murs + 64);
      k_bnapply<<<(N * 64 + 255) / 256, 256, 0, stream>>>(bufA, murs, murs + 64, G[l], BE[l], bufH, N * 64);
      lin = bufH;
    }
  }
}

// Round 6
// 555.513 us; speedup vs baseline: 1.8460x; 1.0269x over previous
//
#include <hip/hip_runtime.h>
#include <hip/hip_fp16.h>
#include <math.h>

constexpr float NEG_SLOPE = 0.2f;
constexpr float EPS_BN = 1e-5f;
constexpr float EPS_SM = 1e-16f;

typedef _Float16 half8 __attribute__((ext_vector_type(8)));
typedef float f32x4 __attribute__((ext_vector_type(4)));

__device__ __forceinline__ float lrelu(float x){ return x >= 0.f ? x : NEG_SLOPE * x; }

// ---------------- utility ----------------
__global__ void k_init(int* cnt, int n, float* bn, int* tick){
  int i = blockIdx.x * blockDim.x + threadIdx.x;
  if (i < n) cnt[i] = 0;
  if (i < 256) bn[i] = 0.f;
  if (i < 4) tick[i] = 0;
}

// all three weight matrices -> fp16, transposed: Wt[n][k]
__global__ void k_convW3(const float* __restrict__ W0, const float* __restrict__ W1,
                         const float* __restrict__ W2, _Float16* __restrict__ Wt0,
                         _Float16* __restrict__ Wt1, _Float16* __restrict__ Wt2){
  int t = blockIdx.x * blockDim.x + threadIdx.x;
  if (t < 65536){
    int n = t & 255, k = t >> 8;
    Wt0[(size_t)n * 256 + k] = (_Float16)W0[(size_t)k * 256 + n];
  } else if (t < 81920){
    int u = t - 65536; int n = u & 255, k = u >> 8;
    Wt1[(size_t)n * 64 + k] = (_Float16)W1[(size_t)k * 256 + n];
  } else if (t < 98304){
    int u = t - 81920; int n = u & 255, k = u >> 8;
    Wt2[(size_t)n * 64 + k] = (_Float16)W2[(size_t)k * 256 + n];
  }
}

// ---------------- CSR build (dst -> list of src), incl. self loops ----------------
__global__ void k_count(const int* __restrict__ ei, int E, int N, int* __restrict__ cnt){
  int e = blockIdx.x * blockDim.x + threadIdx.x;
  if (e >= E + N) return;
  int dst = (e < E) ? ei[E + e] : (e - E);
  atomicAdd(&cnt[dst], 1);
}

__global__ __launch_bounds__(256) void k_blocksum(const int* __restrict__ cnt, int n, int chunk,
                                                  int* __restrict__ part){
  __shared__ int s[256];
  int b = blockIdx.x, t = threadIdx.x;
  int lo = b * chunk, hi = min(n, lo + chunk);
  int v = 0;
  for (int i = lo + t; i < hi; i += 256) v += cnt[i];
  s[t] = v;
  __syncthreads();
  #pragma unroll
  for (int off = 128; off > 0; off >>= 1){
    if (t < off) s[t] += s[t + off];
    __syncthreads();
  }
  if (t == 0) part[b] = s[0];
}

__global__ __launch_bounds__(256) void k_scanpart(int* __restrict__ part, int* __restrict__ ptr, int n){
  __shared__ int s[256];
  int t = threadIdx.x;
  int v = part[t];
  s[t] = v;
  __syncthreads();
  #pragma unroll
  for (int off = 1; off < 256; off <<= 1){
    int u = (t >= off) ? s[t - off] : 0;
    __syncthreads();
    s[t] += u;
    __syncthreads();
  }
  part[t] = s[t] - v;
  if (t == 255) ptr[n] = s[255];
}

__global__ __launch_bounds__(256) void k_localscan(const int* __restrict__ cnt, const int* __restrict__ part,
                                                   int n, int chunk, int* __restrict__ ptr,
                                                   int* __restrict__ cursor){
  __shared__ int s[256];
  int b = blockIdx.x, t = threadIdx.x;
  int i = b * chunk + t;
  int v = (t < chunk && i < n) ? cnt[i] : 0;
  s[t] = v;
  __syncthreads();
  #pragma unroll
  for (int off = 1; off < 256; off <<= 1){
    int u = (t >= off) ? s[t - off] : 0;
    __syncthreads();
    s[t] += u;
    __syncthreads();
  }
  if (t < chunk && i < n){
    int ex = part[b] + s[t] - v;
    ptr[i] = ex;
    cursor[i] = ex;
  }
}

__global__ void k_fill(const int* __restrict__ ei, int E, int N,
                       int* __restrict__ cursor, int* __restrict__ csr_src){
  int e = blockIdx.x * blockDim.x + threadIdx.x;
  if (e >= E + N) return;
  int src, dst;
  if (e < E){ src = ei[e]; dst = ei[E + e]; } else { src = e - E; dst = e - E; }
  int slot = atomicAdd(&cursor[dst], 1);
  csr_src[slot] = src;
}

// ---------------- MFMA GEMM (f32 in w/ optional BN affine+ReLU, fp16 MFMA, f32 acc) ----------------
// Block: 128 rows x 64 cols (one head). scale/shift nullable (layer 0).
__global__ __launch_bounds__(256) void k_gemm(const float* __restrict__ X,
    const _Float16* __restrict__ Wt, const float* __restrict__ a_s, const float* __restrict__ a_d,
    __half* __restrict__ hb, float* __restrict__ al, float* __restrict__ ar, int nrows, int K,
    const float* __restrict__ scale, const float* __restrict__ shift){
  __shared__ _Float16 Alds[4][128][8];  // 8 KB
  __shared__ _Float16 Blds[4][64][8];   // 4 KB
  int tid = threadIdx.x;
  int m0 = blockIdx.x * 128;
  int head = blockIdx.y;
  int n0 = head * 64;
  int w = tid >> 6, l = tid & 63;
  int lm = l & 15, lq = l >> 4;
  int qs = tid & 3, rs = tid >> 2;
  f32x4 acc[2][4] = {};

  for (int k0 = 0; k0 < K; k0 += 32){
    float4 sc0, sc1, sh0, sh1;
    if (scale){
      sc0 = *(const float4*)(scale + k0 + qs * 8);
      sc1 = *(const float4*)(scale + k0 + qs * 8 + 4);
      sh0 = *(const float4*)(shift + k0 + qs * 8);
      sh1 = *(const float4*)(shift + k0 + qs * 8 + 4);
    }
    #pragma unroll
    for (int it = 0; it < 2; it++){
      int row = it * 64 + rs;
      int gr = m0 + row;
      float4 v0 = make_float4(0,0,0,0), v1 = make_float4(0,0,0,0);
      if (gr < nrows){
        v0 = *(const float4*)(X + (size_t)gr * K + k0 + qs * 8);
        v1 = *(const float4*)(X + (size_t)gr * K + k0 + qs * 8 + 4);
      }
      if (scale){
        v0.x = fmaxf(fmaf(v0.x, sc0.x, sh0.x), 0.f);
        v0.y = fmaxf(fmaf(v0.y, sc0.y, sh0.y), 0.f);
        v0.z = fmaxf(fmaf(v0.z, sc0.z, sh0.z), 0.f);
        v0.w = fmaxf(fmaf(v0.w, sc0.w, sh0.w), 0.f);
        v1.x = fmaxf(fmaf(v1.x, sc1.x, sh1.x), 0.f);
        v1.y = fmaxf(fmaf(v1.y, sc1.y, sh1.y), 0.f);
        v1.z = fmaxf(fmaf(v1.z, sc1.z, sh1.z), 0.f);
        v1.w = fmaxf(fmaf(v1.w, sc1.w, sh1.w), 0.f);
      }
      half8 h = {(_Float16)v0.x, (_Float16)v0.y, (_Float16)v0.z, (_Float16)v0.w,
                 (_Float16)v1.x, (_Float16)v1.y, (_Float16)v1.z, (_Float16)v1.w};
      *(half8*)&Alds[qs][row][0] = h;
    }
    *(half8*)&Blds[qs][rs][0] = *(const half8*)(Wt + (size_t)(n0 + rs) * K + k0 + qs * 8);
    __syncthreads();
    half8 af0 = *(const half8*)&Alds[lq][w * 32 + lm][0];
    half8 af1 = *(const half8*)&Alds[lq][w * 32 + 16 + lm][0];
    #pragma unroll
    for (int nt = 0; nt < 4; nt++){
      half8 bf = *(const half8*)&Blds[lq][nt * 16 + lm][0];
      acc[0][nt] = __builtin_amdgcn_mfma_f32_16x16x32_f16(af0, bf, acc[0][nt], 0, 0, 0);
      acc[1][nt] = __builtin_amdgcn_mfma_f32_16x16x32_f16(af1, bf, acc[1][nt], 0, 0, 0);
    }
    __syncthreads();
  }

  float asv[4], adv[4];
  #pragma unroll
  for (int nt = 0; nt < 4; nt++){
    asv[nt] = a_s[n0 + nt * 16 + lm];
    adv[nt] = a_d[n0 + nt * 16 + lm];
  }
  #pragma unroll
  for (int s = 0; s < 2; s++){
    #pragma unroll
    for (int reg = 0; reg < 4; reg++){
      float sl = 0.f, sr = 0.f;
      #pragma unroll
      for (int nt = 0; nt < 4; nt++){
        sl += acc[s][nt][reg] * asv[nt];
        sr += acc[s][nt][reg] * adv[nt];
      }
      #pragma unroll
      for (int off = 1; off < 16; off <<= 1){
        sl += __shfl_xor(sl, off);
        sr += __shfl_xor(sr, off);
      }
      int grow = m0 + w * 32 + s * 16 + lq * 4 + reg;
      if (lm == 0 && grow < nrows){
        al[(size_t)grow * 4 + head] = sl;
        ar[(size_t)grow * 4 + head] = sr;
      }
    }
  }
  #pragma unroll
  for (int s = 0; s < 2; s++){
    #pragma unroll
    for (int nt = 0; nt < 4; nt++){
      #pragma unroll
      for (int reg = 0; reg < 4; reg++){
        int grow = m0 + w * 32 + s * 16 + lq * 4 + reg;
        if (grow < nrows)
          hb[(size_t)grow * 256 + n0 + nt * 16 + lm] = __float2half(acc[s][nt][reg]);
      }
    }
  }
}

// ---------------- per-node softmax + aggregate (wave per node) ----------------
__global__ __launch_bounds__(256) void k_node(const int* __restrict__ ptr,
    const int* __restrict__ csr, const __half* __restrict__ hb,
    const float* __restrict__ al, const float* __restrict__ ar,
    const float* __restrict__ bias, float* __restrict__ out, int N){
  __shared__ int2 ssw[4][64][4];   // per-wave: {src, weight_h} per (edge, head) — 8 KB
  int n = (blockIdx.x * blockDim.x + threadIdx.x) >> 6;
  int lane = threadIdx.x & 63;
  int wv = threadIdx.x >> 6;
  if (n >= N) return;
  int beg = ptr[n], end = ptr[n + 1];
  int deg = end - beg;
  float4 arv = *(const float4*)(ar + (size_t)n * 4);
  int hd = lane >> 4;
  int cg = (lane & 15) * 4;
  const __half* hbase = hb + hd * 64 + cg;
  float ax = 0.f, ay = 0.f, az = 0.f, aw = 0.f;

  if (deg <= 64){
    int idx = beg + lane;
    bool act = idx < end;
    int mye = act ? csr[idx] : 0;
    float e0 = -1e30f, e1 = -1e30f, e2 = -1e30f, e3 = -1e30f;
    if (act){
      float4 av = *(const float4*)(al + (size_t)mye * 4);
      e0 = lrelu(av.x + arv.x); e1 = lrelu(av.y + arv.y);
      e2 = lrelu(av.z + arv.z); e3 = lrelu(av.w + arv.w);
    }
    float m0 = e0, m1 = e1, m2 = e2, m3 = e3;
    #pragma unroll
    for (int off = 32; off > 0; off >>= 1){
      m0 = fmaxf(m0, __shfl_xor(m0, off));
      m1 = fmaxf(m1, __shfl_xor(m1, off));
      m2 = fmaxf(m2, __shfl_xor(m2, off));
      m3 = fmaxf(m3, __shfl_xor(m3, off));
    }
    float w0 = __expf(e0 - m0), w1 = __expf(e1 - m1);
    float w2 = __expf(e2 - m2), w3 = __expf(e3 - m3);
    float d0 = w0, d1 = w1, d2 = w2, d3 = w3;
    #pragma unroll
    for (int off = 32; off > 0; off >>= 1){
      d0 += __shfl_xor(d0, off);
      d1 += __shfl_xor(d1, off);
      d2 += __shfl_xor(d2, off);
      d3 += __shfl_xor(d3, off);
    }
    // stage {src, w_h} interleaved; lane j owns edge j. 2x ds_write_b128.
    int4* wr = (int4*)&ssw[wv][lane][0];
    wr[0] = make_int4(mye, __float_as_int(w0 / (d0 + EPS_SM)),
                      mye, __float_as_int(w1 / (d1 + EPS_SM)));
    wr[1] = make_int4(mye, __float_as_int(w2 / (d2 + EPS_SM)),
                      mye, __float_as_int(w3 / (d3 + EPS_SM)));
    __builtin_amdgcn_wave_barrier();
    const int2* phd = &ssw[wv][0][hd];
    #pragma unroll 4
    for (int j = 0; j < deg; j++){
      int2 sw = phd[j * 4];               // single broadcast ds_read_b64
      float w = __int_as_float(sw.y);
      ushort4 u = *(const ushort4*)(hbase + (size_t)sw.x * 256);
      ax = fmaf(__half2float(__ushort_as_half(u.x)), w, ax);
      ay = fmaf(__half2float(__ushort_as_half(u.y)), w, ay);
      az = fmaf(__half2float(__ushort_as_half(u.z)), w, az);
      aw = fmaf(__half2float(__ushort_as_half(u.w)), w, aw);
    }
  } else {
    float m0 = -1e30f, m1 = -1e30f, m2 = -1e30f, m3 = -1e30f;
    for (int i = beg + lane; i < end; i += 64){
      int s = csr[i];
      float4 av = *(const float4*)(al + (size_t)s * 4);
      m0 = fmaxf(m0, lrelu(av.x + arv.x));
      m1 = fmaxf(m1, lrelu(av.y + arv.y));
      m2 = fmaxf(m2, lrelu(av.z + arv.z));
      m3 = fmaxf(m3, lrelu(av.w + arv.w));
    }
    #pragma unroll
    for (int off = 32; off > 0; off >>= 1){
      m0 = fmaxf(m0, __shfl_xor(m0, off));
      m1 = fmaxf(m1, __shfl_xor(m1, off));
      m2 = fmaxf(m2, __shfl_xor(m2, off));
      m3 = fmaxf(m3, __shfl_xor(m3, off));
    }
    float d0 = 0.f, d1 = 0.f, d2 = 0.f, d3 = 0.f;
    for (int i = beg + lane; i < end; i += 64){
      int s = csr[i];
      float4 av = *(const float4*)(al + (size_t)s * 4);
      d0 += __expf(lrelu(av.x + arv.x) - m0);
      d1 += __expf(lrelu(av.y + arv.y) - m1);
      d2 += __expf(lrelu(av.z + arv.z) - m2);
      d3 += __expf(lrelu(av.w + arv.w) - m3);
    }
    #pragma unroll
    for (int off = 32; off > 0; off >>= 1){
      d0 += __shfl_xor(d0, off);
      d1 += __shfl_xor(d1, off);
      d2 += __shfl_xor(d2, off);
      d3 += __shfl_xor(d3, off);
    }
    float i0 = 1.f / (d0 + EPS_SM), i1 = 1.f / (d1 + EPS_SM);
    float i2 = 1.f / (d2 + EPS_SM), i3 = 1.f / (d3 + EPS_SM);
    float arh = hd == 0 ? arv.x : hd == 1 ? arv.y : hd == 2 ? arv.z : arv.w;
    float mh  = hd == 0 ? m0 : hd == 1 ? m1 : hd == 2 ? m2 : m3;
    float ih  = hd == 0 ? i0 : hd == 1 ? i1 : hd == 2 ? i2 : i3;
    for (int i = beg; i < end; i++){
      int s = csr[i];
      float w = __expf(lrelu(al[(size_t)s * 4 + hd] + arh) - mh) * ih;
      ushort4 u = *(const ushort4*)(hbase + (size_t)s * 256);
      ax = fmaf(__half2float(__ushort_as_half(u.x)), w, ax);
      ay = fmaf(__half2float(__ushort_as_half(u.y)), w, ay);
      az = fmaf(__half2float(__ushort_as_half(u.z)), w, az);
      aw = fmaf(__half2float(__ushort_as_half(u.w)), w, aw);
    }
  }

  #pragma unroll
  for (int off = 16; off <= 32; off <<= 1){
    ax += __shfl_xor(ax, off);
    ay += __shfl_xor(ay, off);
    az += __shfl_xor(az, off);
    aw += __shfl_xor(aw, off);
  }
  if (lane < 16){
    float4 b4 = *(const float4*)(bias + cg);
    *(float4*)(out + (size_t)n * 64 + cg) =
        make_float4(ax * 0.25f + b4.x, ay * 0.25f + b4.y, az * 0.25f + b4.z, aw * 0.25f + b4.w);
  }
}

// ---------------- BatchNorm stats + fused finalize -> scale/shift ----------------
__global__ __launch_bounds__(256) void k_bnstats(const float* __restrict__ x, int N,
                                                 float* __restrict__ gsum, float* __restrict__ gsq,
                                                 int* __restrict__ tick,
                                                 const float* __restrict__ g, const float* __restrict__ be,
                                                 float* __restrict__ scale, float* __restrict__ shift){
  int c = threadIdx.x & 63;
  int rg = threadIdx.x >> 6;
  float s = 0.f, q = 0.f;
  for (int r = blockIdx.x * 4 + rg; r < N; r += gridDim.x * 4){
    float v = x[(size_t)r * 64 + c];
    s += v; q += v * v;
  }
  __shared__ float ls[4][64], lq[4][64];
  __shared__ int amLast;
  ls[rg][c] = s; lq[rg][c] = q;
  __syncthreads();
  if (rg == 0){
    s = ls[0][c] + ls[1][c] + ls[2][c] + ls[3][c];
    q = lq[0][c] + lq[1][c] + lq[2][c] + lq[3][c];
    atomicAdd(&gsum[c], s);
    atomicAdd(&gsq[c], q);
  }
  __threadfence();
  if (threadIdx.x == 0)
    amLast = (atomicAdd(tick, 1) == (int)gridDim.x - 1) ? 1 : 0;
  __syncthreads();
  if (amLast && threadIdx.x < 64){
    float gs = atomicAdd(&gsum[c], 0.f);
    float gq = atomicAdd(&gsq[c], 0.f);
    float m = gs / (float)N;
    float v = gq / (float)N - m * m;
    float sc = g[c] * rsqrtf(v + EPS_BN);
    scale[c] = sc;
    shift[c] = be[c] - m * sc;
  }
}

// ---------------- launcher ----------------
extern "C" void kernel_launch(void* const* d_in, const int* in_sizes, int n_in,
                              void* d_out, int out_size, void* d_ws, size_t ws_size,
                              hipStream_t stream){
  const float* x  = (const float*)d_in[0];
  const int*   ei = (const int*)d_in[1];
  const float* W[3]  = {(const float*)d_in[2], (const float*)d_in[6],  (const float*)d_in[10]};
  const float* AS[3] = {(const float*)d_in[3], (const float*)d_in[7],  (const float*)d_in[11]};
  const float* AD[3] = {(const float*)d_in[4], (const float*)d_in[8],  (const float*)d_in[12]};
  const float* BI[3] = {(const float*)d_in[5], (const float*)d_in[9],  (const float*)d_in[13]};
  const float* G[2]  = {(const float*)d_in[14], (const float*)d_in[16]};
  const float* BE[2] = {(const float*)d_in[15], (const float*)d_in[17]};
  const int N = in_sizes[0] / 256;
  const int E = in_sizes[1] / 2;
  const int EN = E + N;

  char* wsb = (char*)d_ws;
  size_t off = 0;
  auto alloc = [&](size_t bytes) -> char* {
    char* p = wsb + off;
    off = (off + bytes + 255) & ~(size_t)255;
    return p;
  };
  int* cnt      = (int*)alloc((size_t)N * 4);
  int* cursor   = (int*)alloc((size_t)N * 4);
  int* rowptr   = (int*)alloc((size_t)(N + 1) * 4);
  int* part     = (int*)alloc(256 * 4);
  int* csr      = (int*)alloc((size_t)EN * 4);
  _Float16* Wt0 = (_Float16*)alloc((size_t)256 * 256 * 2);
  _Float16* Wt1 = (_Float16*)alloc((size_t)64 * 256 * 2);
  _Float16* Wt2 = (_Float16*)alloc((size_t)64 * 256 * 2);
  __half* hb    = (__half*)alloc((size_t)N * 256 * 2);
  float* al     = (float*)alloc((size_t)N * 4 * 4);
  float* ar     = (float*)alloc((size_t)N * 4 * 4);
  float* bufA   = (float*)alloc((size_t)N * 64 * 4);
  float* bn     = (float*)alloc(256 * 4);
  int*   tick   = (int*)alloc(4 * 4);
  float* murs   = (float*)alloc(128 * 4);   // scale[64], shift[64]

  const int chunk = (N + 255) / 256;

  k_init<<<(N + 255) / 256, 256, 0, stream>>>(cnt, N, bn, tick);
  k_count<<<(EN + 255) / 256, 256, 0, stream>>>(ei, E, N, cnt);
  k_blocksum<<<256, 256, 0, stream>>>(cnt, N, chunk, part);
  k_scanpart<<<1, 256, 0, stream>>>(part, rowptr, N);
  k_localscan<<<256, 256, 0, stream>>>(cnt, part, N, chunk, rowptr, cursor);
  k_fill<<<(EN + 255) / 256, 256, 0, stream>>>(ei, E, N, cursor, csr);
  k_convW3<<<384, 256, 0, stream>>>(W[0], W[1], W[2], Wt0, Wt1, Wt2);

  const _Float16* Wt[3] = {Wt0, Wt1, Wt2};
  const float* lin = x;
  for (int l = 0; l < 3; l++){
    int K = (l == 0) ? 256 : 64;
    const float* sc = (l == 0) ? nullptr : murs;
    const float* sh = (l == 0) ? nullptr : murs + 64;
    dim3 gg((N + 127) / 128, 4);
    k_gemm<<<gg, 256, 0, stream>>>(lin, Wt[l], AS[l], AD[l], hb, al, ar, N, K, sc, sh);
    float* outp = (l == 2) ? (float*)d_out : bufA;
    k_node<<<(N + 3) / 4, 256, 0, stream>>>(rowptr, csr, hb, al, ar, BI[l], outp, N);
    if (l < 2){
      float* gsum = bn + l * 128;
      float* gsq  = gsum + 64;
      k_bnstats<<<128, 256, 0, stream>>>(bufA, N, gsum, gsq, tick + l, G[l], BE[l], murs, murs + 64);
      lin = bufA;
    }
  }
}